// Round 6
// baseline (654.471 us; speedup 1.0000x reference)
//
#include <hip/hip_runtime.h>

typedef short s8v __attribute__((ext_vector_type(8)));
typedef short s4v __attribute__((ext_vector_type(4)));
typedef float f4v __attribute__((ext_vector_type(4)));

#define DEV __device__ __forceinline__

DEV short f2bs(float f){
  unsigned int u = __float_as_uint(f);
  u += 0x7fffu + ((u >> 16) & 1u);
  return (short)(u >> 16);
}
DEV float b2f(short s){
  return __uint_as_float(((unsigned int)(unsigned short)s) << 16);
}
DEV float lrelu(float x){ return x >= 0.f ? x : 0.01f*x; }

// ---------------- K0: weight prep ----------------
__global__ __launch_bounds__(256) void k0_prep(
    const float* __restrict__ w1, const float* __restrict__ w2,
    const float* __restrict__ w3, const float* __restrict__ rw2,
    const float* __restrict__ wq, const float* __restrict__ wk,
    const float* __restrict__ wv, const float* __restrict__ wo,
    char* __restrict__ wreg)
{
  int idx = blockIdx.x*256 + threadIdx.x;
  float* w1T = (float*)(wreg);
  short* w2b = (short*)(wreg + 3456);
  short* w3b = (short*)(wreg + 40320);
  short* rw2b = (short*)(wreg + 114048);
  short* wqb  = (short*)(wreg + 122240);
  short* wkb  = (short*)(wreg + 130432);
  short* wvb  = (short*)(wreg + 138624);
  short* wob  = (short*)(wreg + 146816);
  if (idx < 864){
    int k = idx >> 5, c = idx & 31;
    w1T[idx] = w1[c*27 + k];
  } else if (idx < 19296){
    int j = idx - 864;
    int kk = j / 2048, c = (j >> 5) & 63, ci = j & 31;
    w2b[j] = f2bs(w2[c*288 + ci*9 + kk]);
  } else if (idx < 56160){
    int j = idx - 19296;
    int kk = j / 4096, c = (j >> 6) & 63, ci = j & 63;
    w3b[j] = f2bs(w3[c*576 + ci*9 + kk]);
  } else if (idx < 60256){
    int j = idx - 56160; rw2b[j] = f2bs(rw2[j]);
  } else if (idx < 64352){
    int j = idx - 60256; wqb[j] = f2bs(wq[j]);
  } else if (idx < 68448){
    int j = idx - 64352; wkb[j] = f2bs(wk[j]);
  } else if (idx < 72544){
    int j = idx - 68448; wvb[j] = f2bs(wv[j]);
  } else if (idx < 76640){
    int j = idx - 72544; wob[j] = f2bs(wo[j]);
  }
}

// ---------------- K1: conv1 3->32, stride1, border pad (VALU fp32) ----------------
__global__ __launch_bounds__(256) void k1_conv1(
    const float* __restrict__ vt, short* __restrict__ dst,
    const float* __restrict__ w1T, const float* __restrict__ b1, int v0)
{
  int lane = threadIdx.x & 63, ty = threadIdx.x >> 6;
  int x = blockIdx.x*64 + lane;
  int y = blockIdx.y*4 + ty;
  const float* src = vt + (size_t)(v0 + blockIdx.z)*3*512*512;
  float xin[27];
  #pragma unroll
  for (int ci=0; ci<3; ci++){
    #pragma unroll
    for (int ky=0; ky<3; ky++){
      int iy = min(max(y+ky-1, 0), 511);
      #pragma unroll
      for (int kx=0; kx<3; kx++){
        int ix = min(max(x+kx-1, 0), 511);
        xin[(ci*3+ky)*3+kx] = src[(ci*512 + iy)*512 + ix];
      }
    }
  }
  float acc[32];
  #pragma unroll
  for (int c=0;c<32;c++) acc[c] = b1[c];
  #pragma unroll
  for (int k=0;k<27;k++){
    const float* wr = w1T + k*32;
    #pragma unroll
    for (int c=0;c<32;c++) acc[c] += wr[c]*xin[k];
  }
  s8v pk[4];
  #pragma unroll
  for (int c=0;c<32;c++) pk[c>>3][c&7] = f2bs(lrelu(acc[c]));
  short* o = dst + ((size_t)blockIdx.z*512*512 + (size_t)y*512 + x)*32;
  #pragma unroll
  for (int q=0;q<4;q++) *(s8v*)(o + q*8) = pk[q];
}

// ---------------- conv2/conv3: implicit-GEMM MFMA, stride 2, TILES px-tiles/wave ----------------
template<int CIN, int TILES>
__global__ __launch_bounds__(256) void conv_mfma(
    const short* __restrict__ src0, short* __restrict__ dst,
    const short* __restrict__ wb, const float* __restrict__ bias,
    int IH, int IW, int OW, int dstV0)
{
  const int l = threadIdx.x & 63, w = threadIdx.x >> 6;
  const int p = l & 15, g = l >> 4;
  const int ox0 = blockIdx.x*(64*TILES) + w*(16*TILES) + p;
  const int oy = blockIdx.y;
  const short* src = src0 + (size_t)blockIdx.z*IH*IW*CIN;
  const f4v FZ = {0.f,0.f,0.f,0.f};
  f4v acc[TILES][4];
  #pragma unroll
  for (int tl=0;tl<TILES;tl++)
    #pragma unroll
    for (int m=0;m<4;m++) acc[tl][m] = FZ;
  #pragma unroll
  for (int ky=0;ky<3;ky++){
    int iy = min(max(2*oy+ky-1, 0), IH-1);
    #pragma unroll
    for (int kx=0;kx<3;kx++){
      #pragma unroll
      for (int ch=0; ch<CIN/32; ch++){
        s8v bfrag[TILES];
        #pragma unroll
        for (int tl=0;tl<TILES;tl++){
          int ix = min(max(2*(ox0 + 16*tl)+kx-1, 0), IW-1);
          bfrag[tl] = *(const s8v*)(src + ((size_t)iy*IW + ix)*CIN + ch*32 + g*8);
        }
        #pragma unroll
        for (int m=0;m<4;m++){
          s8v afrag = *(const s8v*)(wb + ((ky*3+kx)*64 + m*16 + p)*CIN + ch*32 + g*8);
          #pragma unroll
          for (int tl=0;tl<TILES;tl++)
            acc[tl][m] = __builtin_amdgcn_mfma_f32_16x16x32_bf16(afrag, bfrag[tl], acc[tl][m], 0,0,0);
        }
      }
    }
  }
  const int OH = gridDim.y;
  #pragma unroll
  for (int tl=0;tl<TILES;tl++){
    short* o = dst + (((size_t)(dstV0 + blockIdx.z)*OH + oy)*OW + ox0 + 16*tl)*64;
    #pragma unroll
    for (int m=0;m<4;m++){
      f4v bb = *(const f4v*)(bias + m*16 + g*4);
      s4v pk;
      #pragma unroll
      for (int r=0;r<4;r++) pk[r] = f2bs(lrelu(acc[tl][m][r] + bb[r]));
      *(s4v*)(o + m*16 + g*4) = pk;
    }
  }
}

// ---------------- K4: parallel bilinear gather ----------------
__global__ __launch_bounds__(256) void k4_gather(
    const short* __restrict__ nts, const float* __restrict__ uvi,
    float* __restrict__ outFeats)
{
  int gid = blockIdx.x*256 + threadIdx.x;
  int tk = gid >> 3, c = (gid & 7)*8;
  const float* up = uvi + (size_t)tk*3;
  float u = up[0], v = up[1];
  int vid = (int)up[2];
  float xf = u*127.f, yf = v*127.f;
  int x0 = min(max((int)floorf(xf), 0), 126);
  int y0 = min(max((int)floorf(yf), 0), 126);
  float wx = xf - (float)x0, wy = yf - (float)y0;
  const short* cb = nts + ((size_t)((vid*128 + y0)*128 + x0))*64 + c;
  s8v c00 = *(const s8v*)(cb);
  s8v c01 = *(const s8v*)(cb + 64);
  s8v c10 = *(const s8v*)(cb + 8192);
  s8v c11 = *(const s8v*)(cb + 8192 + 64);
  f4v o0, o1;
  #pragma unroll
  for (int e=0;e<8;e++){
    float a = b2f(c00[e]); a += wx*(b2f(c01[e]) - a);
    float b = b2f(c10[e]); b += wx*(b2f(c11[e]) - b);
    float val = a + wy*(b - a);
    if (e < 4) o0[e] = val; else o1[e-4] = val;
  }
  float* op = outFeats + (size_t)tk*64 + c;
  *(f4v*)op = o0;
  *(f4v*)(op+4) = o1;
}

// ---------------- K5: rayMLP + MHA (streaming; feats f32 from d_out) ----------------
#define AFRG(W) (*(const s8v*)((W) + (m*16 + p)*64 + kc*32 + g*8))

__global__ __launch_bounds__(256) void k5_attn(
    const float* __restrict__ feats, const float* __restrict__ raydir,
    const float* __restrict__ rw1, const float* __restrict__ rb1,
    const short* __restrict__ rw2b, const float* __restrict__ rb2,
    const short* __restrict__ wqb, const float* __restrict__ bq,
    const short* __restrict__ wkb, const float* __restrict__ bk,
    const short* __restrict__ wvb, const float* __restrict__ bv,
    const short* __restrict__ wob, const float* __restrict__ bo,
    float* __restrict__ outFused)
{
  __shared__ uint4 ldsq[576];
  unsigned int* ldsu = (unsigned int*)ldsq;
  const int l = threadIdx.x & 63, wid = threadIdx.x >> 6;
  const int p = l & 15, g = l >> 4;
  const int pt = blockIdx.x*64 + wid*16 + p;
  const f4v FZ = {0.f,0.f,0.f,0.f};

#define RELAYOUT(H, OB) { \
    _Pragma("unroll") \
    for (int m_=0;m_<4;m_++){ \
      unsigned int lo_ = (unsigned int)(unsigned short)f2bs(H[m_][0]) \
                       | ((unsigned int)(unsigned short)f2bs(H[m_][1])<<16); \
      unsigned int hi_ = (unsigned int)(unsigned short)f2bs(H[m_][2]) \
                       | ((unsigned int)(unsigned short)f2bs(H[m_][3])<<16); \
      int di_ = wid*576 + p*36 + m_*8 + g*2; \
      ldsu[di_] = lo_; ldsu[di_+1] = hi_; \
    } \
    OB[0] = __builtin_bit_cast(s8v, ldsq[wid*144 + p*9 + g]); \
    OB[1] = __builtin_bit_cast(s8v, ldsq[wid*144 + p*9 + 4 + g]); \
  }

  // ---- load feats (f32, coalesced streaming) -> bf16 B-frags ----
  s8v fb[3][2];
  #pragma unroll
  for (int t=0;t<3;t++){
    const float* fp = feats + (size_t)(pt*3+t)*64;
    #pragma unroll
    for (int kc=0;kc<2;kc++){
      f4v a0 = *(const f4v*)(fp + kc*32 + g*8);
      f4v a1 = *(const f4v*)(fp + kc*32 + g*8 + 4);
      s8v tmp;
      #pragma unroll
      for (int e=0;e<4;e++){ tmp[e] = f2bs(a0[e]); tmp[e+4] = f2bs(a1[e]); }
      fb[t][kc] = tmp;
    }
  }

  // ---- ray MLP hidden directly in B-frag layout ----
  float rd0 = raydir[(size_t)pt*3+0];
  float rd1 = raydir[(size_t)pt*3+1];
  float rd2 = raydir[(size_t)pt*3+2];
  s8v xb[2];
  #pragma unroll
  for (int kc=0;kc<2;kc++){
    s8v tmp;
    #pragma unroll
    for (int e=0;e<8;e++){
      int j = kc*32 + g*8 + e;
      float hv = fmaxf(rb1[j] + rw1[j*3]*rd0 + rw1[j*3+1]*rd1 + rw1[j*3+2]*rd2, 0.f);
      tmp[e] = f2bs(hv);
    }
    xb[kc] = tmp;
  }

  // ---- rf = rw2 @ h + rb2 ----
  f4v acc[4];
  #pragma unroll
  for (int m=0;m<4;m++) acc[m] = FZ;
  #pragma unroll
  for (int kc=0;kc<2;kc++){
    #pragma unroll
    for (int m=0;m<4;m++)
      acc[m] = __builtin_amdgcn_mfma_f32_16x16x32_bf16(AFRG(rw2b), xb[kc], acc[m], 0,0,0);
  }
  float rf[4][4];
  #pragma unroll
  for (int m=0;m<4;m++){
    f4v bb = *(const f4v*)(rb2 + m*16 + g*4);
    #pragma unroll
    for (int r=0;r<4;r++) rf[m][r] = acc[m][r] + bb[r];
  }
  RELAYOUT(rf, xb);

  // ---- qh = wq @ rf + bq ----
  #pragma unroll
  for (int m=0;m<4;m++) acc[m] = FZ;
  #pragma unroll
  for (int kc=0;kc<2;kc++){
    #pragma unroll
    for (int m=0;m<4;m++)
      acc[m] = __builtin_amdgcn_mfma_f32_16x16x32_bf16(AFRG(wqb), xb[kc], acc[m], 0,0,0);
  }
  float qh[4][4];
  #pragma unroll
  for (int m=0;m<4;m++){
    f4v bb = *(const f4v*)(bq + m*16 + g*4);
    #pragma unroll
    for (int r=0;r<4;r++) qh[m][r] = acc[m][r] + bb[r];
  }

  // ---- K projections + scores ----
  s8v wkf[2][4];
  #pragma unroll
  for (int kc=0;kc<2;kc++)
    #pragma unroll
    for (int m=0;m<4;m++)
      wkf[kc][m] = AFRG(wkb);

  float sc[3][4];
  #pragma unroll
  for (int t=0;t<3;t++){
    f4v ka[4];
    #pragma unroll
    for (int m=0;m<4;m++) ka[m] = FZ;
    #pragma unroll
    for (int kc=0;kc<2;kc++){
      #pragma unroll
      for (int m=0;m<4;m++)
        ka[m] = __builtin_amdgcn_mfma_f32_16x16x32_bf16(wkf[kc][m], fb[t][kc], ka[m], 0,0,0);
    }
    #pragma unroll
    for (int m=0;m<4;m++){
      f4v bb = *(const f4v*)(bk + m*16 + g*4);
      float part = 0.f;
      #pragma unroll
      for (int r=0;r<4;r++) part += qh[m][r]*(ka[m][r] + bb[r]);
      part += __shfl_xor(part, 16, 64);
      part += __shfl_xor(part, 32, 64);
      sc[t][m] = part*0.25f;
    }
  }

  // ---- softmax over 3 tokens ----
  #pragma unroll
  for (int m=0;m<4;m++){
    float mx = fmaxf(fmaxf(sc[0][m], sc[1][m]), sc[2][m]);
    float e0 = __expf(sc[0][m]-mx);
    float e1 = __expf(sc[1][m]-mx);
    float e2 = __expf(sc[2][m]-mx);
    float inv = 1.f/(e0+e1+e2);
    sc[0][m] = e0*inv; sc[1][m] = e1*inv; sc[2][m] = e2*inv;
  }

  // ---- V projections scaled-accumulated ----
  s8v wvf[2][4];
  #pragma unroll
  for (int kc=0;kc<2;kc++)
    #pragma unroll
    for (int m=0;m<4;m++)
      wvf[kc][m] = AFRG(wvb);

  float o[4][4];
  #pragma unroll
  for (int m=0;m<4;m++)
    #pragma unroll
    for (int r=0;r<4;r++) o[m][r] = 0.f;
  #pragma unroll
  for (int t=0;t<3;t++){
    f4v va[4];
    #pragma unroll
    for (int m=0;m<4;m++) va[m] = FZ;
    #pragma unroll
    for (int kc=0;kc<2;kc++){
      #pragma unroll
      for (int m=0;m<4;m++)
        va[m] = __builtin_amdgcn_mfma_f32_16x16x32_bf16(wvf[kc][m], fb[t][kc], va[m], 0,0,0);
    }
    #pragma unroll
    for (int m=0;m<4;m++)
      #pragma unroll
      for (int r=0;r<4;r++) o[m][r] += sc[t][m]*va[m][r];
  }
  #pragma unroll
  for (int m=0;m<4;m++){
    f4v bb = *(const f4v*)(bv + m*16 + g*4);
    #pragma unroll
    for (int r=0;r<4;r++) o[m][r] += bb[r];
  }
  RELAYOUT(o, xb);

  // ---- out = wo @ o + bo ----
  #pragma unroll
  for (int m=0;m<4;m++) acc[m] = FZ;
  #pragma unroll
  for (int kc=0;kc<2;kc++){
    #pragma unroll
    for (int m=0;m<4;m++)
      acc[m] = __builtin_amdgcn_mfma_f32_16x16x32_bf16(AFRG(wob), xb[kc], acc[m], 0,0,0);
  }
  #pragma unroll
  for (int m=0;m<4;m++){
    f4v bb = *(const f4v*)(bo + m*16 + g*4);
    f4v res;
    #pragma unroll
    for (int r=0;r<4;r++) res[r] = acc[m][r] + bb[r];
    *(f4v*)(outFused + (size_t)pt*64 + m*16 + g*4) = res;
  }
#undef RELAYOUT
}

extern "C" void kernel_launch(void* const* d_in, const int* in_sizes, int n_in,
                              void* d_out, int out_size, void* d_ws, size_t ws_size,
                              hipStream_t stream)
{
  const float* view_tex = (const float*)d_in[0];
  const float* uvi    = (const float*)d_in[1];
  const float* raydir = (const float*)d_in[2];
  const float* w1 = (const float*)d_in[3];
  const float* b1 = (const float*)d_in[4];
  const float* w2 = (const float*)d_in[5];
  const float* b2 = (const float*)d_in[6];
  const float* w3 = (const float*)d_in[7];
  const float* b3 = (const float*)d_in[8];
  const float* rw1 = (const float*)d_in[9];
  const float* rb1 = (const float*)d_in[10];
  const float* rw2 = (const float*)d_in[11];
  const float* rb2 = (const float*)d_in[12];
  const float* wq = (const float*)d_in[13];
  const float* bq = (const float*)d_in[14];
  const float* wk = (const float*)d_in[15];
  const float* bk = (const float*)d_in[16];
  const float* wv = (const float*)d_in[17];
  const float* bv = (const float*)d_in[18];
  const float* wo = (const float*)d_in[19];
  const float* bo = (const float*)d_in[20];
  float* out = (float*)d_out;

  const int V = in_sizes[0] / (3*512*512);     // 8
  const int B = in_sizes[1] / 9;               // 262144
  const size_t FEATS_OFF = (size_t)B*64;

  const size_t C1F  = (size_t)V*512*512*32*2;
  const size_t C2F  = (size_t)V*256*256*64*2;
  const size_t C1V  = (size_t)512*512*32*2;
  const size_t C2V  = (size_t)256*256*64*2;
  const size_t NTSB = (size_t)V*128*128*64*2;
  const size_t WREG = 262144;

  char* base = (char*)d_ws;
  bool full = (ws_size >= C1F + C2F + NTSB + WREG);

  char *c1, *c2, *ntsp, *wreg;
  if (full){
    c1 = base; c2 = c1 + C1F; ntsp = c2 + C2F; wreg = ntsp + NTSB;
  } else {
    c1 = base; c2 = c1 + C1V; ntsp = c2 + C2V; wreg = ntsp + NTSB;
  }
  float* w1T = (float*)(wreg);
  short* w2b = (short*)(wreg + 3456);
  short* w3b = (short*)(wreg + 40320);
  short* rw2b = (short*)(wreg + 114048);
  short* wqb  = (short*)(wreg + 122240);
  short* wkb  = (short*)(wreg + 130432);
  short* wvb  = (short*)(wreg + 138624);
  short* wob  = (short*)(wreg + 146816);

  k0_prep<<<dim3(300),256,0,stream>>>(w1,w2,w3,rw2,wq,wk,wv,wo,wreg);

  if (full){
    k1_conv1<<<dim3(8,128,V),256,0,stream>>>(view_tex,(short*)c1,w1T,b1,0);
    // ATTRIBUTION PROBE: conv2 and conv3 launched 3x (idempotent, serialized).
    // conv2+conv3 time = (total_us - 397) / 2.
    for (int rep=0; rep<3; rep++)
      conv_mfma<32,4><<<dim3(1,256,V),256,0,stream>>>((const short*)c1,(short*)c2,w2b,b2,512,512,256,0);
    for (int rep=0; rep<3; rep++)
      conv_mfma<64,2><<<dim3(1,128,V),256,0,stream>>>((const short*)c2,(short*)ntsp,w3b,b3,256,256,128,0);
  } else {
    for (int v=0; v<V; v++){
      k1_conv1<<<dim3(8,128,1),256,0,stream>>>(view_tex,(short*)c1,w1T,b1,v);
      conv_mfma<32,4><<<dim3(1,256,1),256,0,stream>>>((const short*)c1,(short*)c2,w2b,b2,512,512,256,0);
      conv_mfma<64,2><<<dim3(1,128,1),256,0,stream>>>((const short*)c2,(short*)ntsp,w3b,b3,256,256,128,v);
    }
  }

  k4_gather<<<dim3((B*3*8)/256),256,0,stream>>>((const short*)ntsp, uvi, out + FEATS_OFF);

  k5_attn<<<dim3(B/64),256,0,stream>>>(out + FEATS_OFF, raydir,
      rw1, rb1, rw2b, rb2, wqb, bq, wkb, bk, wvb, bv, wob, bo, out);
}

// Round 7
// 470.546 us; speedup vs baseline: 1.3909x; 1.3909x over previous
//
#include <hip/hip_runtime.h>

typedef short s8v __attribute__((ext_vector_type(8)));
typedef short s4v __attribute__((ext_vector_type(4)));
typedef float f4v __attribute__((ext_vector_type(4)));

#define DEV __device__ __forceinline__

DEV short f2bs(float f){
  unsigned int u = __float_as_uint(f);
  u += 0x7fffu + ((u >> 16) & 1u);
  return (short)(u >> 16);
}
DEV float b2f(short s){
  return __uint_as_float(((unsigned int)(unsigned short)s) << 16);
}
DEV float lrelu(float x){ return x >= 0.f ? x : 0.01f*x; }

// ---------------- K0: weight prep ----------------
// w2b/w3b now in MFMA FRAGMENT ORDER: [tap][m][kc][lane(64)][e(8)]
//   lane l -> cout = m*16 + (l&15), cin = kc*32 + (l>>4)*8 + e
__global__ __launch_bounds__(256) void k0_prep(
    const float* __restrict__ w1, const float* __restrict__ w2,
    const float* __restrict__ w3, const float* __restrict__ rw2,
    const float* __restrict__ wq, const float* __restrict__ wk,
    const float* __restrict__ wv, const float* __restrict__ wo,
    char* __restrict__ wreg)
{
  int idx = blockIdx.x*256 + threadIdx.x;
  float* w1T = (float*)(wreg);
  short* w2b = (short*)(wreg + 3456);
  short* w3b = (short*)(wreg + 40320);
  short* rw2b = (short*)(wreg + 114048);
  short* wqb  = (short*)(wreg + 122240);
  short* wkb  = (short*)(wreg + 130432);
  short* wvb  = (short*)(wreg + 138624);
  short* wob  = (short*)(wreg + 146816);
  if (idx < 864){
    int k = idx >> 5, c = idx & 31;
    w1T[idx] = w1[c*27 + k];
  } else if (idx < 19296){
    int j = idx - 864;                      // [0,18432)
    int e = j & 7, l = (j >> 3) & 63, r = j >> 9;   // r in [0,36)
    int m = r & 3, tap = r >> 2;
    int cout = m*16 + (l & 15), cin = (l >> 4)*8 + e;
    w2b[j] = f2bs(w2[(cout*32 + cin)*9 + tap]);
  } else if (idx < 56160){
    int j = idx - 19296;                    // [0,36864)
    int e = j & 7, l = (j >> 3) & 63, r = j >> 9;   // r in [0,72)
    int kc = r & 1, m = (r >> 1) & 3, tap = r >> 3;
    int cout = m*16 + (l & 15), cin = kc*32 + (l >> 4)*8 + e;
    w3b[j] = f2bs(w3[(cout*64 + cin)*9 + tap]);
  } else if (idx < 60256){
    int j = idx - 56160; rw2b[j] = f2bs(rw2[j]);
  } else if (idx < 64352){
    int j = idx - 60256; wqb[j] = f2bs(wq[j]);
  } else if (idx < 68448){
    int j = idx - 64352; wkb[j] = f2bs(wk[j]);
  } else if (idx < 72544){
    int j = idx - 68448; wvb[j] = f2bs(wv[j]);
  } else if (idx < 76640){
    int j = idx - 72544; wob[j] = f2bs(wo[j]);
  }
}

// ---------------- K1: conv1 3->32, 2 px/thread (vertical pair) ----------------
// Each weight s_load feeds 2 independent FMA chains; input rows shared.
__global__ __launch_bounds__(256) void k1_conv1(
    const float* __restrict__ vt, short* __restrict__ dst,
    const float* __restrict__ w1T, const float* __restrict__ b1, int v0)
{
  int lane = threadIdx.x & 63, ty = threadIdx.x >> 6;
  int x = blockIdx.x*64 + lane;
  int y0 = blockIdx.y*8 + ty*2;
  const float* src = vt + (size_t)(v0 + blockIdx.z)*3*512*512;
  float xin[3][4][3];
  #pragma unroll
  for (int ci=0; ci<3; ci++){
    #pragma unroll
    for (int ry=0; ry<4; ry++){
      int iy = min(max(y0+ry-1, 0), 511);
      #pragma unroll
      for (int cx=0; cx<3; cx++){
        int ix = min(max(x+cx-1, 0), 511);
        xin[ci][ry][cx] = src[((size_t)ci*512 + iy)*512 + ix];
      }
    }
  }
  float acc0[32], acc1[32];
  #pragma unroll
  for (int c=0;c<32;c++){ acc0[c] = b1[c]; acc1[c] = b1[c]; }
  #pragma unroll
  for (int ci=0;ci<3;ci++){
    #pragma unroll
    for (int ky=0;ky<3;ky++){
      #pragma unroll
      for (int kx=0;kx<3;kx++){
        const float* wr = w1T + ((ci*3+ky)*3+kx)*32;
        float x0 = xin[ci][ky][kx], x1 = xin[ci][ky+1][kx];
        #pragma unroll
        for (int c=0;c<32;c++){
          acc0[c] += wr[c]*x0;
          acc1[c] += wr[c]*x1;
        }
      }
    }
  }
  short* o0 = dst + ((size_t)blockIdx.z*512*512 + (size_t)y0*512 + x)*32;
  s8v pk[4];
  #pragma unroll
  for (int c=0;c<32;c++) pk[c>>3][c&7] = f2bs(lrelu(acc0[c]));
  #pragma unroll
  for (int q=0;q<4;q++) *(s8v*)(o0 + q*8) = pk[q];
  #pragma unroll
  for (int c=0;c<32;c++) pk[c>>3][c&7] = f2bs(lrelu(acc1[c]));
  short* o1 = o0 + 512*32;
  #pragma unroll
  for (int q=0;q<4;q++) *(s8v*)(o1 + q*8) = pk[q];
}

// ---------------- conv2/conv3: MFMA, LDS-staged weights (double-buffered per tap) ----------------
// wb is in fragment order [tap][m][kc][lane][8]. Per-tap shorts = 4*(CIN/32)*512.
template<int CIN, int TILES>
__global__ __launch_bounds__(256) void conv_mfma(
    const short* __restrict__ src0, short* __restrict__ dst,
    const short* __restrict__ wb, const float* __restrict__ bias,
    int IH, int IW, int OW, int dstV0)
{
  constexpr int KC = CIN/32;
  constexpr int TAPS = 4*KC*512;            // shorts per tap (2048 / 4096)
  __shared__ short wlds[2][TAPS];
  const int tid = threadIdx.x;
  const int l = tid & 63, w = tid >> 6;
  const int p = l & 15, g = l >> 4;
  const int ox0 = blockIdx.x*(64*TILES) + w*(16*TILES) + p;
  const int oy = blockIdx.y;
  const short* src = src0 + (size_t)blockIdx.z*IH*IW*CIN;
  const f4v FZ = {0.f,0.f,0.f,0.f};
  f4v acc[TILES][4];
  #pragma unroll
  for (int tl=0;tl<TILES;tl++)
    #pragma unroll
    for (int m=0;m<4;m++) acc[tl][m] = FZ;

  // stage tap 0
  #pragma unroll
  for (int off = 0; off < TAPS; off += 2048){
    s8v v = *(const s8v*)(wb + off + tid*8);
    *(s8v*)(&wlds[0][off + tid*8]) = v;
  }

  #pragma unroll
  for (int tap=0; tap<9; tap++){
    __syncthreads();
    if (tap < 8){
      #pragma unroll
      for (int off = 0; off < TAPS; off += 2048){
        s8v v = *(const s8v*)(wb + (tap+1)*TAPS + off + tid*8);
        *(s8v*)(&wlds[(tap+1)&1][off + tid*8]) = v;
      }
    }
    const int ky = tap/3, kx = tap%3;
    const int iy = min(max(2*oy+ky-1, 0), IH-1);
    const short* wbuf = &wlds[tap&1][0];
    #pragma unroll
    for (int kc=0; kc<KC; kc++){
      s8v bfrag[TILES];
      #pragma unroll
      for (int tl=0;tl<TILES;tl++){
        int ix = min(max(2*(ox0 + 16*tl)+kx-1, 0), IW-1);
        bfrag[tl] = *(const s8v*)(src + ((size_t)iy*IW + ix)*CIN + kc*32 + g*8);
      }
      #pragma unroll
      for (int m=0;m<4;m++){
        s8v afrag = *(const s8v*)(wbuf + ((m*KC + kc)*64 + l)*8);
        #pragma unroll
        for (int tl=0;tl<TILES;tl++)
          acc[tl][m] = __builtin_amdgcn_mfma_f32_16x16x32_bf16(afrag, bfrag[tl], acc[tl][m], 0,0,0);
      }
    }
  }
  const int OH = gridDim.y;
  #pragma unroll
  for (int tl=0;tl<TILES;tl++){
    short* o = dst + (((size_t)(dstV0 + blockIdx.z)*OH + oy)*OW + ox0 + 16*tl)*64;
    #pragma unroll
    for (int m=0;m<4;m++){
      f4v bb = *(const f4v*)(bias + m*16 + g*4);
      s4v pk;
      #pragma unroll
      for (int r=0;r<4;r++) pk[r] = f2bs(lrelu(acc[tl][m][r] + bb[r]));
      *(s4v*)(o + m*16 + g*4) = pk;
    }
  }
}

// ---------------- K4: parallel bilinear gather ----------------
__global__ __launch_bounds__(256) void k4_gather(
    const short* __restrict__ nts, const float* __restrict__ uvi,
    float* __restrict__ outFeats)
{
  int gid = blockIdx.x*256 + threadIdx.x;
  int tk = gid >> 3, c = (gid & 7)*8;
  const float* up = uvi + (size_t)tk*3;
  float u = up[0], v = up[1];
  int vid = (int)up[2];
  float xf = u*127.f, yf = v*127.f;
  int x0 = min(max((int)floorf(xf), 0), 126);
  int y0 = min(max((int)floorf(yf), 0), 126);
  float wx = xf - (float)x0, wy = yf - (float)y0;
  const short* cb = nts + ((size_t)((vid*128 + y0)*128 + x0))*64 + c;
  s8v c00 = *(const s8v*)(cb);
  s8v c01 = *(const s8v*)(cb + 64);
  s8v c10 = *(const s8v*)(cb + 8192);
  s8v c11 = *(const s8v*)(cb + 8192 + 64);
  f4v o0, o1;
  #pragma unroll
  for (int e=0;e<8;e++){
    float a = b2f(c00[e]); a += wx*(b2f(c01[e]) - a);
    float b = b2f(c10[e]); b += wx*(b2f(c11[e]) - b);
    float val = a + wy*(b - a);
    if (e < 4) o0[e] = val; else o1[e-4] = val;
  }
  float* op = outFeats + (size_t)tk*64 + c;
  *(f4v*)op = o0;
  *(f4v*)(op+4) = o1;
}

// ---------------- K5: rayMLP + MHA (streaming; feats f32 from d_out) ----------------
#define AFRG(W) (*(const s8v*)((W) + (m*16 + p)*64 + kc*32 + g*8))

__global__ __launch_bounds__(256) void k5_attn(
    const float* __restrict__ feats, const float* __restrict__ raydir,
    const float* __restrict__ rw1, const float* __restrict__ rb1,
    const short* __restrict__ rw2b, const float* __restrict__ rb2,
    const short* __restrict__ wqb, const float* __restrict__ bq,
    const short* __restrict__ wkb, const float* __restrict__ bk,
    const short* __restrict__ wvb, const float* __restrict__ bv,
    const short* __restrict__ wob, const float* __restrict__ bo,
    float* __restrict__ outFused)
{
  __shared__ uint4 ldsq[576];
  unsigned int* ldsu = (unsigned int*)ldsq;
  const int l = threadIdx.x & 63, wid = threadIdx.x >> 6;
  const int p = l & 15, g = l >> 4;
  const int pt = blockIdx.x*64 + wid*16 + p;
  const f4v FZ = {0.f,0.f,0.f,0.f};

#define RELAYOUT(H, OB) { \
    _Pragma("unroll") \
    for (int m_=0;m_<4;m_++){ \
      unsigned int lo_ = (unsigned int)(unsigned short)f2bs(H[m_][0]) \
                       | ((unsigned int)(unsigned short)f2bs(H[m_][1])<<16); \
      unsigned int hi_ = (unsigned int)(unsigned short)f2bs(H[m_][2]) \
                       | ((unsigned int)(unsigned short)f2bs(H[m_][3])<<16); \
      int di_ = wid*576 + p*36 + m_*8 + g*2; \
      ldsu[di_] = lo_; ldsu[di_+1] = hi_; \
    } \
    OB[0] = __builtin_bit_cast(s8v, ldsq[wid*144 + p*9 + g]); \
    OB[1] = __builtin_bit_cast(s8v, ldsq[wid*144 + p*9 + 4 + g]); \
  }

  s8v fb[3][2];
  #pragma unroll
  for (int t=0;t<3;t++){
    const float* fp = feats + (size_t)(pt*3+t)*64;
    #pragma unroll
    for (int kc=0;kc<2;kc++){
      f4v a0 = *(const f4v*)(fp + kc*32 + g*8);
      f4v a1 = *(const f4v*)(fp + kc*32 + g*8 + 4);
      s8v tmp;
      #pragma unroll
      for (int e=0;e<4;e++){ tmp[e] = f2bs(a0[e]); tmp[e+4] = f2bs(a1[e]); }
      fb[t][kc] = tmp;
    }
  }

  float rd0 = raydir[(size_t)pt*3+0];
  float rd1 = raydir[(size_t)pt*3+1];
  float rd2 = raydir[(size_t)pt*3+2];
  s8v xb[2];
  #pragma unroll
  for (int kc=0;kc<2;kc++){
    s8v tmp;
    #pragma unroll
    for (int e=0;e<8;e++){
      int j = kc*32 + g*8 + e;
      float hv = fmaxf(rb1[j] + rw1[j*3]*rd0 + rw1[j*3+1]*rd1 + rw1[j*3+2]*rd2, 0.f);
      tmp[e] = f2bs(hv);
    }
    xb[kc] = tmp;
  }

  f4v acc[4];
  #pragma unroll
  for (int m=0;m<4;m++) acc[m] = FZ;
  #pragma unroll
  for (int kc=0;kc<2;kc++){
    #pragma unroll
    for (int m=0;m<4;m++)
      acc[m] = __builtin_amdgcn_mfma_f32_16x16x32_bf16(AFRG(rw2b), xb[kc], acc[m], 0,0,0);
  }
  float rf[4][4];
  #pragma unroll
  for (int m=0;m<4;m++){
    f4v bb = *(const f4v*)(rb2 + m*16 + g*4);
    #pragma unroll
    for (int r=0;r<4;r++) rf[m][r] = acc[m][r] + bb[r];
  }
  RELAYOUT(rf, xb);

  #pragma unroll
  for (int m=0;m<4;m++) acc[m] = FZ;
  #pragma unroll
  for (int kc=0;kc<2;kc++){
    #pragma unroll
    for (int m=0;m<4;m++)
      acc[m] = __builtin_amdgcn_mfma_f32_16x16x32_bf16(AFRG(wqb), xb[kc], acc[m], 0,0,0);
  }
  float qh[4][4];
  #pragma unroll
  for (int m=0;m<4;m++){
    f4v bb = *(const f4v*)(bq + m*16 + g*4);
    #pragma unroll
    for (int r=0;r<4;r++) qh[m][r] = acc[m][r] + bb[r];
  }

  s8v wkf[2][4];
  #pragma unroll
  for (int kc=0;kc<2;kc++)
    #pragma unroll
    for (int m=0;m<4;m++)
      wkf[kc][m] = AFRG(wkb);

  float sc[3][4];
  #pragma unroll
  for (int t=0;t<3;t++){
    f4v ka[4];
    #pragma unroll
    for (int m=0;m<4;m++) ka[m] = FZ;
    #pragma unroll
    for (int kc=0;kc<2;kc++){
      #pragma unroll
      for (int m=0;m<4;m++)
        ka[m] = __builtin_amdgcn_mfma_f32_16x16x32_bf16(wkf[kc][m], fb[t][kc], ka[m], 0,0,0);
    }
    #pragma unroll
    for (int m=0;m<4;m++){
      f4v bb = *(const f4v*)(bk + m*16 + g*4);
      float part = 0.f;
      #pragma unroll
      for (int r=0;r<4;r++) part += qh[m][r]*(ka[m][r] + bb[r]);
      part += __shfl_xor(part, 16, 64);
      part += __shfl_xor(part, 32, 64);
      sc[t][m] = part*0.25f;
    }
  }

  #pragma unroll
  for (int m=0;m<4;m++){
    float mx = fmaxf(fmaxf(sc[0][m], sc[1][m]), sc[2][m]);
    float e0 = __expf(sc[0][m]-mx);
    float e1 = __expf(sc[1][m]-mx);
    float e2 = __expf(sc[2][m]-mx);
    float inv = 1.f/(e0+e1+e2);
    sc[0][m] = e0*inv; sc[1][m] = e1*inv; sc[2][m] = e2*inv;
  }

  s8v wvf[2][4];
  #pragma unroll
  for (int kc=0;kc<2;kc++)
    #pragma unroll
    for (int m=0;m<4;m++)
      wvf[kc][m] = AFRG(wvb);

  float o[4][4];
  #pragma unroll
  for (int m=0;m<4;m++)
    #pragma unroll
    for (int r=0;r<4;r++) o[m][r] = 0.f;
  #pragma unroll
  for (int t=0;t<3;t++){
    f4v va[4];
    #pragma unroll
    for (int m=0;m<4;m++) va[m] = FZ;
    #pragma unroll
    for (int kc=0;kc<2;kc++){
      #pragma unroll
      for (int m=0;m<4;m++)
        va[m] = __builtin_amdgcn_mfma_f32_16x16x32_bf16(wvf[kc][m], fb[t][kc], va[m], 0,0,0);
    }
    #pragma unroll
    for (int m=0;m<4;m++)
      #pragma unroll
      for (int r=0;r<4;r++) o[m][r] += sc[t][m]*va[m][r];
  }
  #pragma unroll
  for (int m=0;m<4;m++){
    f4v bb = *(const f4v*)(bv + m*16 + g*4);
    #pragma unroll
    for (int r=0;r<4;r++) o[m][r] += bb[r];
  }
  RELAYOUT(o, xb);

  #pragma unroll
  for (int m=0;m<4;m++) acc[m] = FZ;
  #pragma unroll
  for (int kc=0;kc<2;kc++){
    #pragma unroll
    for (int m=0;m<4;m++)
      acc[m] = __builtin_amdgcn_mfma_f32_16x16x32_bf16(AFRG(wob), xb[kc], acc[m], 0,0,0);
  }
  #pragma unroll
  for (int m=0;m<4;m++){
    f4v bb = *(const f4v*)(bo + m*16 + g*4);
    f4v res;
    #pragma unroll
    for (int r=0;r<4;r++) res[r] = acc[m][r] + bb[r];
    *(f4v*)(outFused + (size_t)pt*64 + m*16 + g*4) = res;
  }
#undef RELAYOUT
}

extern "C" void kernel_launch(void* const* d_in, const int* in_sizes, int n_in,
                              void* d_out, int out_size, void* d_ws, size_t ws_size,
                              hipStream_t stream)
{
  const float* view_tex = (const float*)d_in[0];
  const float* uvi    = (const float*)d_in[1];
  const float* raydir = (const float*)d_in[2];
  const float* w1 = (const float*)d_in[3];
  const float* b1 = (const float*)d_in[4];
  const float* w2 = (const float*)d_in[5];
  const float* b2 = (const float*)d_in[6];
  const float* w3 = (const float*)d_in[7];
  const float* b3 = (const float*)d_in[8];
  const float* rw1 = (const float*)d_in[9];
  const float* rb1 = (const float*)d_in[10];
  const float* rw2 = (const float*)d_in[11];
  const float* rb2 = (const float*)d_in[12];
  const float* wq = (const float*)d_in[13];
  const float* bq = (const float*)d_in[14];
  const float* wk = (const float*)d_in[15];
  const float* bk = (const float*)d_in[16];
  const float* wv = (const float*)d_in[17];
  const float* bv = (const float*)d_in[18];
  const float* wo = (const float*)d_in[19];
  const float* bo = (const float*)d_in[20];
  float* out = (float*)d_out;

  const int V = in_sizes[0] / (3*512*512);     // 8
  const int B = in_sizes[1] / 9;               // 262144
  const size_t FEATS_OFF = (size_t)B*64;

  const size_t C1F  = (size_t)V*512*512*32*2;
  const size_t C2F  = (size_t)V*256*256*64*2;
  const size_t C1V  = (size_t)512*512*32*2;
  const size_t C2V  = (size_t)256*256*64*2;
  const size_t NTSB = (size_t)V*128*128*64*2;
  const size_t WREG = 262144;

  char* base = (char*)d_ws;
  bool full = (ws_size >= C1F + C2F + NTSB + WREG);

  char *c1, *c2, *ntsp, *wreg;
  if (full){
    c1 = base; c2 = c1 + C1F; ntsp = c2 + C2F; wreg = ntsp + NTSB;
  } else {
    c1 = base; c2 = c1 + C1V; ntsp = c2 + C2V; wreg = ntsp + NTSB;
  }
  float* w1T = (float*)(wreg);
  short* w2b = (short*)(wreg + 3456);
  short* w3b = (short*)(wreg + 40320);
  short* rw2b = (short*)(wreg + 114048);
  short* wqb  = (short*)(wreg + 122240);
  short* wkb  = (short*)(wreg + 130432);
  short* wvb  = (short*)(wreg + 138624);
  short* wob  = (short*)(wreg + 146816);

  k0_prep<<<dim3(300),256,0,stream>>>(w1,w2,w3,rw2,wq,wk,wv,wo,wreg);

  if (full){
    k1_conv1<<<dim3(8,64,V),256,0,stream>>>(view_tex,(short*)c1,w1T,b1,0);
    conv_mfma<32,4><<<dim3(1,256,V),256,0,stream>>>((const short*)c1,(short*)c2,w2b,b2,512,512,256,0);
    conv_mfma<64,2><<<dim3(1,128,V),256,0,stream>>>((const short*)c2,(short*)ntsp,w3b,b3,256,256,128,0);
  } else {
    for (int v=0; v<V; v++){
      k1_conv1<<<dim3(8,64,1),256,0,stream>>>(view_tex,(short*)c1,w1T,b1,v);
      conv_mfma<32,4><<<dim3(1,256,1),256,0,stream>>>((const short*)c1,(short*)c2,w2b,b2,512,512,256,0);
      conv_mfma<64,2><<<dim3(1,128,1),256,0,stream>>>((const short*)c2,(short*)ntsp,w3b,b3,256,256,128,v);
    }
  }

  k4_gather<<<dim3((B*3*8)/256),256,0,stream>>>((const short*)ntsp, uvi, out + FEATS_OFF);

  k5_attn<<<dim3(B/64),256,0,stream>>>(out + FEATS_OFF, raydir,
      rw1, rb1, rw2b, rb2, wqb, bq, wkb, bk, wvb, bv, wob, bo, out);
}

// Round 8
// 387.059 us; speedup vs baseline: 1.6909x; 1.2157x over previous
//
#include <hip/hip_runtime.h>

typedef short s8v __attribute__((ext_vector_type(8)));
typedef short s4v __attribute__((ext_vector_type(4)));
typedef float f4v __attribute__((ext_vector_type(4)));

#define DEV __device__ __forceinline__

DEV short f2bs(float f){
  unsigned int u = __float_as_uint(f);
  u += 0x7fffu + ((u >> 16) & 1u);
  return (short)(u >> 16);
}
DEV float b2f(short s){
  return __uint_as_float(((unsigned int)(unsigned short)s) << 16);
}
DEV float lrelu(float x){ return x >= 0.f ? x : 0.01f*x; }

// ---------------- K0: weight prep ----------------
// wreg layout (bytes):
//   0      w1b  bf16 [m(2)][lane(64)][e(8)]  (2048 B; k=(lane>>4)*8+e, k>=27 -> 0)
//   3456   w2b  bf16 [tap][cout64][cin32]
//   40320  w3b  bf16 [tap][cout64][cin64]
//   114048 rw2b / 122240 wqb / 130432 wkb / 138624 wvb / 146816 wob
__global__ __launch_bounds__(256) void k0_prep(
    const float* __restrict__ w1, const float* __restrict__ w2,
    const float* __restrict__ w3, const float* __restrict__ rw2,
    const float* __restrict__ wq, const float* __restrict__ wk,
    const float* __restrict__ wv, const float* __restrict__ wo,
    char* __restrict__ wreg)
{
  int idx = blockIdx.x*256 + threadIdx.x;
  short* w1b = (short*)(wreg);
  short* w2b = (short*)(wreg + 3456);
  short* w3b = (short*)(wreg + 40320);
  short* rw2b = (short*)(wreg + 114048);
  short* wqb  = (short*)(wreg + 122240);
  short* wkb  = (short*)(wreg + 130432);
  short* wvb  = (short*)(wreg + 138624);
  short* wob  = (short*)(wreg + 146816);
  if (idx < 1024){
    int e = idx & 7, l = (idx >> 3) & 63, m = idx >> 9;
    int k = (l >> 4)*8 + e;
    int cout = m*16 + (l & 15);
    w1b[idx] = (k < 27) ? f2bs(w1[cout*27 + k]) : (short)0;
  } else if (idx < 19456){
    int j = idx - 1024;
    int kk = j / 2048, c = (j >> 5) & 63, ci = j & 31;
    w2b[j] = f2bs(w2[c*288 + ci*9 + kk]);
  } else if (idx < 56320){
    int j = idx - 19456;
    int kk = j / 4096, c = (j >> 6) & 63, ci = j & 63;
    w3b[j] = f2bs(w3[c*576 + ci*9 + kk]);
  } else if (idx < 60416){
    int j = idx - 56320; rw2b[j] = f2bs(rw2[j]);
  } else if (idx < 64512){
    int j = idx - 60416; wqb[j] = f2bs(wq[j]);
  } else if (idx < 68608){
    int j = idx - 64512; wkb[j] = f2bs(wk[j]);
  } else if (idx < 72704){
    int j = idx - 68608; wvb[j] = f2bs(wv[j]);
  } else if (idx < 76800){
    int j = idx - 72704; wob[j] = f2bs(wo[j]);
  }
}

// ---------------- K1: conv1 3->32, MFMA implicit-GEMM with LDS input staging ----------------
// Block: 64 wide x 8 rows output tile. LDS: [3][10][72] bf16 halo tile.
// Wave w: rows 2w..2w+1, 4 col-tiles of 16 px. K=27 padded to 32.
__global__ __launch_bounds__(256) void k1_conv1m(
    const float* __restrict__ vt, short* __restrict__ dst,
    const short* __restrict__ w1b, const float* __restrict__ b1, int v0)
{
  __shared__ short xtile[2160];               // 3*10*72
  const int tid = threadIdx.x;
  const int l = tid & 63, w = tid >> 6;
  const int p = l & 15, g = l >> 4;
  const int x0 = blockIdx.x*64, y0 = blockIdx.y*8;
  const float* src = vt + (size_t)(v0 + blockIdx.z)*3*512*512;

  // ---- stage halo tile (fp32 -> bf16), coalesced ----
  for (int it=0; it<9; it++){
    int idx = it*256 + tid;
    if (idx < 2160){
      int ci = idx/720, rem = idx - ci*720;
      int row = rem/72, col = rem - row*72;
      if (col < 66){
        int grow = min(max(y0-1+row, 0), 511);
        int gcol = min(max(x0-1+col, 0), 511);
        xtile[idx] = f2bs(src[((size_t)ci*512 + grow)*512 + gcol]);
      } else {
        xtile[idx] = 0;                       // pad cols: keep finite
      }
    }
  }

  // ---- per-lane loop-invariant B-frag LDS offsets ----
  int boff[8];
  #pragma unroll
  for (int e=0;e<8;e++){
    int k = g*8 + e;
    int ci = (k*57) >> 9;                     // k/9 for k<32
    int r9 = k - ci*9;
    int ky = (r9*11) >> 5;                    // r9/3
    int kx = r9 - ky*3;
    boff[e] = (k < 27) ? (ci*720 + ky*72 + kx) : 0;   // invalid -> slot 0 (A row is 0)
  }

  s8v af0 = *(const s8v*)(w1b + l*8);
  s8v af1 = *(const s8v*)(w1b + 512 + l*8);
  const f4v FZ = {0.f,0.f,0.f,0.f};
  f4v bb0 = *(const f4v*)(b1 + g*4);
  f4v bb1 = *(const f4v*)(b1 + 16 + g*4);

  __syncthreads();

  #pragma unroll
  for (int rr=0; rr<2; rr++){
    const int r = w*2 + rr;
    #pragma unroll
    for (int tx=0; tx<4; tx++){
      const int px = tx*16 + p;
      const int base = r*72 + px;
      s8v bf;
      #pragma unroll
      for (int e=0;e<8;e++) bf[e] = xtile[boff[e] + base];
      f4v a0 = __builtin_amdgcn_mfma_f32_16x16x32_bf16(af0, bf, FZ, 0,0,0);
      f4v a1 = __builtin_amdgcn_mfma_f32_16x16x32_bf16(af1, bf, FZ, 0,0,0);
      short* o = dst + ((size_t)blockIdx.z*512*512 + (size_t)(y0+r)*512 + (x0+px))*32;
      s4v pk;
      #pragma unroll
      for (int q=0;q<4;q++) pk[q] = f2bs(lrelu(a0[q] + bb0[q]));
      *(s4v*)(o + g*4) = pk;
      #pragma unroll
      for (int q=0;q<4;q++) pk[q] = f2bs(lrelu(a1[q] + bb1[q]));
      *(s4v*)(o + 16 + g*4) = pk;
    }
  }
}

// ---------------- conv2/conv3: implicit-GEMM MFMA, stride 2, TILES px-tiles/wave ----------------
template<int CIN, int TILES>
__global__ __launch_bounds__(256) void conv_mfma(
    const short* __restrict__ src0, short* __restrict__ dst,
    const short* __restrict__ wb, const float* __restrict__ bias,
    int IH, int IW, int OW, int dstV0)
{
  const int l = threadIdx.x & 63, w = threadIdx.x >> 6;
  const int p = l & 15, g = l >> 4;
  const int ox0 = blockIdx.x*(64*TILES) + w*(16*TILES) + p;
  const int oy = blockIdx.y;
  const short* src = src0 + (size_t)blockIdx.z*IH*IW*CIN;
  const f4v FZ = {0.f,0.f,0.f,0.f};
  f4v acc[TILES][4];
  #pragma unroll
  for (int tl=0;tl<TILES;tl++)
    #pragma unroll
    for (int m=0;m<4;m++) acc[tl][m] = FZ;
  #pragma unroll
  for (int ky=0;ky<3;ky++){
    int iy = min(max(2*oy+ky-1, 0), IH-1);
    #pragma unroll
    for (int kx=0;kx<3;kx++){
      #pragma unroll
      for (int ch=0; ch<CIN/32; ch++){
        s8v bfrag[TILES];
        #pragma unroll
        for (int tl=0;tl<TILES;tl++){
          int ix = min(max(2*(ox0 + 16*tl)+kx-1, 0), IW-1);
          bfrag[tl] = *(const s8v*)(src + ((size_t)iy*IW + ix)*CIN + ch*32 + g*8);
        }
        #pragma unroll
        for (int m=0;m<4;m++){
          s8v afrag = *(const s8v*)(wb + ((ky*3+kx)*64 + m*16 + p)*CIN + ch*32 + g*8);
          #pragma unroll
          for (int tl=0;tl<TILES;tl++)
            acc[tl][m] = __builtin_amdgcn_mfma_f32_16x16x32_bf16(afrag, bfrag[tl], acc[tl][m], 0,0,0);
        }
      }
    }
  }
  const int OH = gridDim.y;
  #pragma unroll
  for (int tl=0;tl<TILES;tl++){
    short* o = dst + (((size_t)(dstV0 + blockIdx.z)*OH + oy)*OW + ox0 + 16*tl)*64;
    #pragma unroll
    for (int m=0;m<4;m++){
      f4v bb = *(const f4v*)(bias + m*16 + g*4);
      s4v pk;
      #pragma unroll
      for (int r=0;r<4;r++) pk[r] = f2bs(lrelu(acc[tl][m][r] + bb[r]));
      *(s4v*)(o + m*16 + g*4) = pk;
    }
  }
}

// ---------------- K4: parallel bilinear gather ----------------
__global__ __launch_bounds__(256) void k4_gather(
    const short* __restrict__ nts, const float* __restrict__ uvi,
    float* __restrict__ outFeats)
{
  int gid = blockIdx.x*256 + threadIdx.x;
  int tk = gid >> 3, c = (gid & 7)*8;
  const float* up = uvi + (size_t)tk*3;
  float u = up[0], v = up[1];
  int vid = (int)up[2];
  float xf = u*127.f, yf = v*127.f;
  int x0 = min(max((int)floorf(xf), 0), 126);
  int y0 = min(max((int)floorf(yf), 0), 126);
  float wx = xf - (float)x0, wy = yf - (float)y0;
  const short* cb = nts + ((size_t)((vid*128 + y0)*128 + x0))*64 + c;
  s8v c00 = *(const s8v*)(cb);
  s8v c01 = *(const s8v*)(cb + 64);
  s8v c10 = *(const s8v*)(cb + 8192);
  s8v c11 = *(const s8v*)(cb + 8192 + 64);
  f4v o0, o1;
  #pragma unroll
  for (int e=0;e<8;e++){
    float a = b2f(c00[e]); a += wx*(b2f(c01[e]) - a);
    float b = b2f(c10[e]); b += wx*(b2f(c11[e]) - b);
    float val = a + wy*(b - a);
    if (e < 4) o0[e] = val; else o1[e-4] = val;
  }
  float* op = outFeats + (size_t)tk*64 + c;
  *(f4v*)op = o0;
  *(f4v*)(op+4) = o1;
}

// ---------------- K5: rayMLP + MHA (streaming; feats f32 from d_out) ----------------
#define AFRG(W) (*(const s8v*)((W) + (m*16 + p)*64 + kc*32 + g*8))

__global__ __launch_bounds__(256) void k5_attn(
    const float* __restrict__ feats, const float* __restrict__ raydir,
    const float* __restrict__ rw1, const float* __restrict__ rb1,
    const short* __restrict__ rw2b, const float* __restrict__ rb2,
    const short* __restrict__ wqb, const float* __restrict__ bq,
    const short* __restrict__ wkb, const float* __restrict__ bk,
    const short* __restrict__ wvb, const float* __restrict__ bv,
    const short* __restrict__ wob, const float* __restrict__ bo,
    float* __restrict__ outFused)
{
  __shared__ uint4 ldsq[576];
  unsigned int* ldsu = (unsigned int*)ldsq;
  const int l = threadIdx.x & 63, wid = threadIdx.x >> 6;
  const int p = l & 15, g = l >> 4;
  const int pt = blockIdx.x*64 + wid*16 + p;
  const f4v FZ = {0.f,0.f,0.f,0.f};

#define RELAYOUT(H, OB) { \
    _Pragma("unroll") \
    for (int m_=0;m_<4;m_++){ \
      unsigned int lo_ = (unsigned int)(unsigned short)f2bs(H[m_][0]) \
                       | ((unsigned int)(unsigned short)f2bs(H[m_][1])<<16); \
      unsigned int hi_ = (unsigned int)(unsigned short)f2bs(H[m_][2]) \
                       | ((unsigned int)(unsigned short)f2bs(H[m_][3])<<16); \
      int di_ = wid*576 + p*36 + m_*8 + g*2; \
      ldsu[di_] = lo_; ldsu[di_+1] = hi_; \
    } \
    OB[0] = __builtin_bit_cast(s8v, ldsq[wid*144 + p*9 + g]); \
    OB[1] = __builtin_bit_cast(s8v, ldsq[wid*144 + p*9 + 4 + g]); \
  }

  s8v fb[3][2];
  #pragma unroll
  for (int t=0;t<3;t++){
    const float* fp = feats + (size_t)(pt*3+t)*64;
    #pragma unroll
    for (int kc=0;kc<2;kc++){
      f4v a0 = *(const f4v*)(fp + kc*32 + g*8);
      f4v a1 = *(const f4v*)(fp + kc*32 + g*8 + 4);
      s8v tmp;
      #pragma unroll
      for (int e=0;e<4;e++){ tmp[e] = f2bs(a0[e]); tmp[e+4] = f2bs(a1[e]); }
      fb[t][kc] = tmp;
    }
  }

  float rd0 = raydir[(size_t)pt*3+0];
  float rd1 = raydir[(size_t)pt*3+1];
  float rd2 = raydir[(size_t)pt*3+2];
  s8v xb[2];
  #pragma unroll
  for (int kc=0;kc<2;kc++){
    s8v tmp;
    #pragma unroll
    for (int e=0;e<8;e++){
      int j = kc*32 + g*8 + e;
      float hv = fmaxf(rb1[j] + rw1[j*3]*rd0 + rw1[j*3+1]*rd1 + rw1[j*3+2]*rd2, 0.f);
      tmp[e] = f2bs(hv);
    }
    xb[kc] = tmp;
  }

  f4v acc[4];
  #pragma unroll
  for (int m=0;m<4;m++) acc[m] = FZ;
  #pragma unroll
  for (int kc=0;kc<2;kc++){
    #pragma unroll
    for (int m=0;m<4;m++)
      acc[m] = __builtin_amdgcn_mfma_f32_16x16x32_bf16(AFRG(rw2b), xb[kc], acc[m], 0,0,0);
  }
  float rf[4][4];
  #pragma unroll
  for (int m=0;m<4;m++){
    f4v bb = *(const f4v*)(rb2 + m*16 + g*4);
    #pragma unroll
    for (int r=0;r<4;r++) rf[m][r] = acc[m][r] + bb[r];
  }
  RELAYOUT(rf, xb);

  #pragma unroll
  for (int m=0;m<4;m++) acc[m] = FZ;
  #pragma unroll
  for (int kc=0;kc<2;kc++){
    #pragma unroll
    for (int m=0;m<4;m++)
      acc[m] = __builtin_amdgcn_mfma_f32_16x16x32_bf16(AFRG(wqb), xb[kc], acc[m], 0,0,0);
  }
  float qh[4][4];
  #pragma unroll
  for (int m=0;m<4;m++){
    f4v bb = *(const f4v*)(bq + m*16 + g*4);
    #pragma unroll
    for (int r=0;r<4;r++) qh[m][r] = acc[m][r] + bb[r];
  }

  s8v wkf[2][4];
  #pragma unroll
  for (int kc=0;kc<2;kc++)
    #pragma unroll
    for (int m=0;m<4;m++)
      wkf[kc][m] = AFRG(wkb);

  float sc[3][4];
  #pragma unroll
  for (int t=0;t<3;t++){
    f4v ka[4];
    #pragma unroll
    for (int m=0;m<4;m++) ka[m] = FZ;
    #pragma unroll
    for (int kc=0;kc<2;kc++){
      #pragma unroll
      for (int m=0;m<4;m++)
        ka[m] = __builtin_amdgcn_mfma_f32_16x16x32_bf16(wkf[kc][m], fb[t][kc], ka[m], 0,0,0);
    }
    #pragma unroll
    for (int m=0;m<4;m++){
      f4v bb = *(const f4v*)(bk + m*16 + g*4);
      float part = 0.f;
      #pragma unroll
      for (int r=0;r<4;r++) part += qh[m][r]*(ka[m][r] + bb[r]);
      part += __shfl_xor(part, 16, 64);
      part += __shfl_xor(part, 32, 64);
      sc[t][m] = part*0.25f;
    }
  }

  #pragma unroll
  for (int m=0;m<4;m++){
    float mx = fmaxf(fmaxf(sc[0][m], sc[1][m]), sc[2][m]);
    float e0 = __expf(sc[0][m]-mx);
    float e1 = __expf(sc[1][m]-mx);
    float e2 = __expf(sc[2][m]-mx);
    float inv = 1.f/(e0+e1+e2);
    sc[0][m] = e0*inv; sc[1][m] = e1*inv; sc[2][m] = e2*inv;
  }

  s8v wvf[2][4];
  #pragma unroll
  for (int kc=0;kc<2;kc++)
    #pragma unroll
    for (int m=0;m<4;m++)
      wvf[kc][m] = AFRG(wvb);

  float o[4][4];
  #pragma unroll
  for (int m=0;m<4;m++)
    #pragma unroll
    for (int r=0;r<4;r++) o[m][r] = 0.f;
  #pragma unroll
  for (int t=0;t<3;t++){
    f4v va[4];
    #pragma unroll
    for (int m=0;m<4;m++) va[m] = FZ;
    #pragma unroll
    for (int kc=0;kc<2;kc++){
      #pragma unroll
      for (int m=0;m<4;m++)
        va[m] = __builtin_amdgcn_mfma_f32_16x16x32_bf16(wvf[kc][m], fb[t][kc], va[m], 0,0,0);
    }
    #pragma unroll
    for (int m=0;m<4;m++)
      #pragma unroll
      for (int r=0;r<4;r++) o[m][r] += sc[t][m]*va[m][r];
  }
  #pragma unroll
  for (int m=0;m<4;m++){
    f4v bb = *(const f4v*)(bv + m*16 + g*4);
    #pragma unroll
    for (int r=0;r<4;r++) o[m][r] += bb[r];
  }
  RELAYOUT(o, xb);

  #pragma unroll
  for (int m=0;m<4;m++) acc[m] = FZ;
  #pragma unroll
  for (int kc=0;kc<2;kc++){
    #pragma unroll
    for (int m=0;m<4;m++)
      acc[m] = __builtin_amdgcn_mfma_f32_16x16x32_bf16(AFRG(wob), xb[kc], acc[m], 0,0,0);
  }
  #pragma unroll
  for (int m=0;m<4;m++){
    f4v bb = *(const f4v*)(bo + m*16 + g*4);
    f4v res;
    #pragma unroll
    for (int r=0;r<4;r++) res[r] = acc[m][r] + bb[r];
    *(f4v*)(outFused + (size_t)pt*64 + m*16 + g*4) = res;
  }
#undef RELAYOUT
}

extern "C" void kernel_launch(void* const* d_in, const int* in_sizes, int n_in,
                              void* d_out, int out_size, void* d_ws, size_t ws_size,
                              hipStream_t stream)
{
  const float* view_tex = (const float*)d_in[0];
  const float* uvi    = (const float*)d_in[1];
  const float* raydir = (const float*)d_in[2];
  const float* w1 = (const float*)d_in[3];
  const float* b1 = (const float*)d_in[4];
  const float* w2 = (const float*)d_in[5];
  const float* b2 = (const float*)d_in[6];
  const float* w3 = (const float*)d_in[7];
  const float* b3 = (const float*)d_in[8];
  const float* rw1 = (const float*)d_in[9];
  const float* rb1 = (const float*)d_in[10];
  const float* rw2 = (const float*)d_in[11];
  const float* rb2 = (const float*)d_in[12];
  const float* wq = (const float*)d_in[13];
  const float* bq = (const float*)d_in[14];
  const float* wk = (const float*)d_in[15];
  const float* bk = (const float*)d_in[16];
  const float* wv = (const float*)d_in[17];
  const float* bv = (const float*)d_in[18];
  const float* wo = (const float*)d_in[19];
  const float* bo = (const float*)d_in[20];
  float* out = (float*)d_out;

  const int V = in_sizes[0] / (3*512*512);     // 8
  const int B = in_sizes[1] / 9;               // 262144
  const size_t FEATS_OFF = (size_t)B*64;

  const size_t C1F  = (size_t)V*512*512*32*2;
  const size_t C2F  = (size_t)V*256*256*64*2;
  const size_t C1V  = (size_t)512*512*32*2;
  const size_t C2V  = (size_t)256*256*64*2;
  const size_t NTSB = (size_t)V*128*128*64*2;
  const size_t WREG = 262144;

  char* base = (char*)d_ws;
  bool full = (ws_size >= C1F + C2F + NTSB + WREG);

  char *c1, *c2, *ntsp, *wreg;
  if (full){
    c1 = base; c2 = c1 + C1F; ntsp = c2 + C2F; wreg = ntsp + NTSB;
  } else {
    c1 = base; c2 = c1 + C1V; ntsp = c2 + C2V; wreg = ntsp + NTSB;
  }
  short* w1b = (short*)(wreg);
  short* w2b = (short*)(wreg + 3456);
  short* w3b = (short*)(wreg + 40320);
  short* rw2b = (short*)(wreg + 114048);
  short* wqb  = (short*)(wreg + 122240);
  short* wkb  = (short*)(wreg + 130432);
  short* wvb  = (short*)(wreg + 138624);
  short* wob  = (short*)(wreg + 146816);

  k0_prep<<<dim3(300),256,0,stream>>>(w1,w2,w3,rw2,wq,wk,wv,wo,wreg);

  if (full){
    k1_conv1m<<<dim3(8,64,V),256,0,stream>>>(view_tex,(short*)c1,w1b,b1,0);
    conv_mfma<32,4><<<dim3(1,256,V),256,0,stream>>>((const short*)c1,(short*)c2,w2b,b2,512,512,256,0);
    conv_mfma<64,2><<<dim3(1,128,V),256,0,stream>>>((const short*)c2,(short*)ntsp,w3b,b3,256,256,128,0);
  } else {
    for (int v=0; v<V; v++){
      k1_conv1m<<<dim3(8,64,1),256,0,stream>>>(view_tex,(short*)c1,w1b,b1,v);
      conv_mfma<32,4><<<dim3(1,256,1),256,0,stream>>>((const short*)c1,(short*)c2,w2b,b2,512,512,256,0);
      conv_mfma<64,2><<<dim3(1,128,1),256,0,stream>>>((const short*)c2,(short*)ntsp,w3b,b3,256,256,128,v);
    }
  }

  k4_gather<<<dim3((B*3*8)/256),256,0,stream>>>((const short*)ntsp, uvi, out + FEATS_OFF);

  k5_attn<<<dim3(B/64),256,0,stream>>>(out + FEATS_OFF, raydir,
      rw1, rb1, rw2b, rb2, wqb, bq, wkb, bk, wvb, bv, wob, bo, out);
}

// Round 10
// 339.897 us; speedup vs baseline: 1.9255x; 1.1388x over previous
//
#include <hip/hip_runtime.h>

typedef short s8v __attribute__((ext_vector_type(8)));
typedef short s4v __attribute__((ext_vector_type(4)));
typedef float f4v __attribute__((ext_vector_type(4)));

#define DEV __device__ __forceinline__

DEV short f2bs(float f){
  unsigned int u = __float_as_uint(f);
  u += 0x7fffu + ((u >> 16) & 1u);
  return (short)(u >> 16);
}
DEV float b2f(short s){
  return __uint_as_float(((unsigned int)(unsigned short)s) << 16);
}
DEV float lrelu(float x){ return x >= 0.f ? x : 0.01f*x; }
DEV unsigned pk2(float a, float b){
  return (unsigned)(unsigned short)f2bs(a) | ((unsigned)(unsigned short)f2bs(b) << 16);
}

// ---------------- K0: weight prep ----------------
// wreg layout (bytes):
//   0      w1b  bf16 [m(2)][lane(64)][e(8)]  (2048 B; k=(lane>>4)*8+e, k>=27 -> 0)
//   3456   w2b  bf16 [tap][cout64][cin32]
//   40320  w3b  bf16 [tap][cout64][cin64]
//   114048 rw2b / 122240 wqb / 130432 wkb / 138624 wvb / 146816 wob
__global__ __launch_bounds__(256) void k0_prep(
    const float* __restrict__ w1, const float* __restrict__ w2,
    const float* __restrict__ w3, const float* __restrict__ rw2,
    const float* __restrict__ wq, const float* __restrict__ wk,
    const float* __restrict__ wv, const float* __restrict__ wo,
    char* __restrict__ wreg)
{
  int idx = blockIdx.x*256 + threadIdx.x;
  short* w1b = (short*)(wreg);
  short* w2b = (short*)(wreg + 3456);
  short* w3b = (short*)(wreg + 40320);
  short* rw2b = (short*)(wreg + 114048);
  short* wqb  = (short*)(wreg + 122240);
  short* wkb  = (short*)(wreg + 130432);
  short* wvb  = (short*)(wreg + 138624);
  short* wob  = (short*)(wreg + 146816);
  if (idx < 1024){
    int e = idx & 7, l = (idx >> 3) & 63, m = idx >> 9;
    int k = (l >> 4)*8 + e;
    int cout = m*16 + (l & 15);
    w1b[idx] = (k < 27) ? f2bs(w1[cout*27 + k]) : (short)0;
  } else if (idx < 19456){
    int j = idx - 1024;
    int kk = j / 2048, c = (j >> 5) & 63, ci = j & 31;
    w2b[j] = f2bs(w2[c*288 + ci*9 + kk]);
  } else if (idx < 56320){
    int j = idx - 19456;
    int kk = j / 4096, c = (j >> 6) & 63, ci = j & 63;
    w3b[j] = f2bs(w3[c*576 + ci*9 + kk]);
  } else if (idx < 60416){
    int j = idx - 56320; rw2b[j] = f2bs(rw2[j]);
  } else if (idx < 64512){
    int j = idx - 60416; wqb[j] = f2bs(wq[j]);
  } else if (idx < 68608){
    int j = idx - 64512; wkb[j] = f2bs(wk[j]);
  } else if (idx < 72704){
    int j = idx - 68608; wvb[j] = f2bs(wv[j]);
  } else if (idx < 76800){
    int j = idx - 72704; wob[j] = f2bs(wo[j]);
  }
}

// ---------------- KC12: fused conv1+conv2 ----------------
// Block tile: conv2 64 cols x 2 rows. Waves: wid>>1 = row, wid&1 = col-half (32 cols).
// srcT: [3][7][148] bf16 halo (clamped at staging). Per-wave rowbuf [80][36] bf16.
// For ky=0..2: MFMA conv1 row (5 strips) -> rowbuf -> conv2 taps accumulate.
__global__ __launch_bounds__(256) void kc12(
    const float* __restrict__ vt, short* __restrict__ c2,
    const short* __restrict__ w1b, const float* __restrict__ b1,
    const short* __restrict__ w2b, const float* __restrict__ b2, int v0)
{
  __shared__ short srcT[3108];
  __shared__ short rb[4][2880];
  const int tid = threadIdx.x;
  const int l = tid & 63, wid = tid >> 6;
  const int p = l & 15, g = l >> 4;
  const int OXB = blockIdx.x*64, OYB = blockIdx.y*2;
  const float* src = vt + (size_t)(v0 + blockIdx.z)*3*512*512;

  // ---- stage src halo tile (coalesced fp32 -> bf16, clamped) ----
  #pragma unroll
  for (int it=0; it<13; it++){
    int idx = it*256 + tid;
    if (idx < 3108){
      int ci = idx/1036, rem = idx - ci*1036;
      int row = rem/148, col = rem - row*148;
      int gr = min(max(2*OYB - 2 + row, 0), 511);
      int gc = min(max(2*OXB - 2 + col, 0), 511);
      srcT[idx] = f2bs(src[((size_t)ci*512 + gr)*512 + gc]);
    }
  }

  // ---- per-lane conv1 tap offsets (loop-invariant) ----
  int boffB[8];
  #pragma unroll
  for (int e=0;e<8;e++){
    int k = g*8 + e;
    int ci = (k*57) >> 9;                 // k/9
    int r9 = k - ci*9;
    int dy = (r9*11) >> 5;                // r9/3
    int dx = r9 - dy*3;
    boffB[e] = (k < 27) ? (ci*1036 + dy*148 + dx) : 0;
  }
  s8v af0 = *(const s8v*)(w1b + l*8);
  s8v af1 = *(const s8v*)(w1b + 512 + l*8);
  f4v cb0 = *(const f4v*)(b1 + g*4);
  f4v cb1 = *(const f4v*)(b1 + 16 + g*4);

  const int dlt = wid >> 1, h = wid & 1;
  const int oy = OYB + dlt;
  const int ox0 = OXB + h*32;
  const int Cw0 = 2*ox0 - 1;
  short* myrb = rb[wid];
  const f4v FZ = {0.f,0.f,0.f,0.f};
  f4v acc[2][4];
  #pragma unroll
  for (int s2=0;s2<2;s2++)
    #pragma unroll
    for (int m=0;m<4;m++) acc[s2][m] = FZ;

  __syncthreads();

  #pragma unroll
  for (int ky=0; ky<3; ky++){
    const int R = min(max(2*oy + ky - 1, 0), 511);
    const int trb = R - 2*OYB + 1;              // tile row for dy=0
    const int sbase = trb*148 + 64*h + p;

    // ---- conv1 row -> rowbuf (bias + lrelu applied) ----
    #pragma unroll
    for (int s=0; s<5; s++){
      s8v bf;
      #pragma unroll
      for (int e=0;e<8;e++) bf[e] = srcT[boffB[e] + sbase + s*16];
      f4v d0 = __builtin_amdgcn_mfma_f32_16x16x32_bf16(af0, bf, FZ, 0,0,0);
      f4v d1 = __builtin_amdgcn_mfma_f32_16x16x32_bf16(af1, bf, FZ, 0,0,0);
      int wcol = s*16 + p;
      uint2 wa = { pk2(lrelu(d0[0]+cb0[0]), lrelu(d0[1]+cb0[1])),
                   pk2(lrelu(d0[2]+cb0[2]), lrelu(d0[3]+cb0[3])) };
      *(uint2*)(myrb + wcol*36 + g*4) = wa;
      uint2 wb2 = { pk2(lrelu(d1[0]+cb1[0]), lrelu(d1[1]+cb1[1])),
                    pk2(lrelu(d1[2]+cb1[2]), lrelu(d1[3]+cb1[3])) };
      *(uint2*)(myrb + wcol*36 + 16 + g*4) = wb2;
    }

    // ---- conv2 taps for this conv1 row ----
    #pragma unroll
    for (int s2=0; s2<2; s2++){
      const int locox = s2*16 + p;
      #pragma unroll
      for (int kx=0; kx<3; kx++){
        int raw = Cw0 + 2*locox + kx;
        int ri = max(raw, 0) - Cw0;             // left-edge border clamp
        uint2 lo2 = *(const uint2*)(myrb + ri*36 + g*8);
        uint2 hi2 = *(const uint2*)(myrb + ri*36 + g*8 + 4);
        uint4 t4 = {lo2.x, lo2.y, hi2.x, hi2.y};
        s8v bf2 = __builtin_bit_cast(s8v, t4);
        #pragma unroll
        for (int m=0;m<4;m++){
          s8v afr = *(const s8v*)(w2b + ((ky*3+kx)*64 + m*16 + p)*32 + g*8);
          acc[s2][m] = __builtin_amdgcn_mfma_f32_16x16x32_bf16(afr, bf2, acc[s2][m], 0,0,0);
        }
      }
    }
  }

  // ---- epilogue: bias + lrelu -> c2 [v][256][256][64] ----
  #pragma unroll
  for (int s2=0; s2<2; s2++){
    short* o = c2 + (((size_t)blockIdx.z*256 + oy)*256 + ox0 + s2*16 + p)*64;
    #pragma unroll
    for (int m=0;m<4;m++){
      f4v bb = *(const f4v*)(b2 + m*16 + g*4);
      s4v pk;
      #pragma unroll
      for (int r=0;r<4;r++) pk[r] = f2bs(lrelu(acc[s2][m][r] + bb[r]));
      *(s4v*)(o + m*16 + g*4) = pk;
    }
  }
}

// ---------------- conv3: implicit-GEMM MFMA, stride 2, TILES px-tiles/wave ----------------
template<int CIN, int TILES>
__global__ __launch_bounds__(256) void conv_mfma(
    const short* __restrict__ src0, short* __restrict__ dst,
    const short* __restrict__ wb, const float* __restrict__ bias,
    int IH, int IW, int OW, int dstV0)
{
  const int l = threadIdx.x & 63, w = threadIdx.x >> 6;
  const int p = l & 15, g = l >> 4;
  const int ox0 = blockIdx.x*(64*TILES) + w*(16*TILES) + p;
  const int oy = blockIdx.y;
  const short* src = src0 + (size_t)blockIdx.z*IH*IW*CIN;
  const f4v FZ = {0.f,0.f,0.f,0.f};
  f4v acc[TILES][4];
  #pragma unroll
  for (int tl=0;tl<TILES;tl++)
    #pragma unroll
    for (int m=0;m<4;m++) acc[tl][m] = FZ;
  #pragma unroll
  for (int ky=0;ky<3;ky++){
    int iy = min(max(2*oy+ky-1, 0), IH-1);
    #pragma unroll
    for (int kx=0;kx<3;kx++){
      #pragma unroll
      for (int ch=0; ch<CIN/32; ch++){
        s8v bfrag[TILES];
        #pragma unroll
        for (int tl=0;tl<TILES;tl++){
          int ix = min(max(2*(ox0 + 16*tl)+kx-1, 0), IW-1);
          bfrag[tl] = *(const s8v*)(src + ((size_t)iy*IW + ix)*CIN + ch*32 + g*8);
        }
        #pragma unroll
        for (int m=0;m<4;m++){
          s8v afrag = *(const s8v*)(wb + ((ky*3+kx)*64 + m*16 + p)*CIN + ch*32 + g*8);
          #pragma unroll
          for (int tl=0;tl<TILES;tl++)
            acc[tl][m] = __builtin_amdgcn_mfma_f32_16x16x32_bf16(afrag, bfrag[tl], acc[tl][m], 0,0,0);
        }
      }
    }
  }
  const int OH = gridDim.y;
  #pragma unroll
  for (int tl=0;tl<TILES;tl++){
    short* o = dst + (((size_t)(dstV0 + blockIdx.z)*OH + oy)*OW + ox0 + 16*tl)*64;
    #pragma unroll
    for (int m=0;m<4;m++){
      f4v bb = *(const f4v*)(bias + m*16 + g*4);
      s4v pk;
      #pragma unroll
      for (int r=0;r<4;r++) pk[r] = f2bs(lrelu(acc[tl][m][r] + bb[r]));
      *(s4v*)(o + m*16 + g*4) = pk;
    }
  }
}

// ---------------- K4: parallel bilinear gather ----------------
__global__ __launch_bounds__(256) void k4_gather(
    const short* __restrict__ nts, const float* __restrict__ uvi,
    float* __restrict__ outFeats)
{
  int gid = blockIdx.x*256 + threadIdx.x;
  int tk = gid >> 3, c = (gid & 7)*8;
  const float* up = uvi + (size_t)tk*3;
  float u = up[0], v = up[1];
  int vid = (int)up[2];
  float xf = u*127.f, yf = v*127.f;
  int x0 = min(max((int)floorf(xf), 0), 126);
  int y0 = min(max((int)floorf(yf), 0), 126);
  float wx = xf - (float)x0, wy = yf - (float)y0;
  const short* cb = nts + ((size_t)((vid*128 + y0)*128 + x0))*64 + c;
  s8v c00 = *(const s8v*)(cb);
  s8v c01 = *(const s8v*)(cb + 64);
  s8v c10 = *(const s8v*)(cb + 8192);
  s8v c11 = *(const s8v*)(cb + 8192 + 64);
  f4v o0, o1;
  #pragma unroll
  for (int e=0;e<8;e++){
    float a = b2f(c00[e]); a += wx*(b2f(c01[e]) - a);
    float b = b2f(c10[e]); b += wx*(b2f(c11[e]) - b);
    float val = a + wy*(b - a);
    if (e < 4) o0[e] = val; else o1[e-4] = val;
  }
  float* op = outFeats + (size_t)tk*64 + c;
  *(f4v*)op = o0;
  *(f4v*)(op+4) = o1;
}

// ---------------- K5: rayMLP + MHA (streaming; feats f32 from d_out) ----------------
#define AFRG(W) (*(const s8v*)((W) + (m*16 + p)*64 + kc*32 + g*8))

__global__ __launch_bounds__(256) void k5_attn(
    const float* __restrict__ feats, const float* __restrict__ raydir,
    const float* __restrict__ rw1, const float* __restrict__ rb1,
    const short* __restrict__ rw2b, const float* __restrict__ rb2,
    const short* __restrict__ wqb, const float* __restrict__ bq,
    const short* __restrict__ wkb, const float* __restrict__ bk,
    const short* __restrict__ wvb, const float* __restrict__ bv,
    const short* __restrict__ wob, const float* __restrict__ bo,
    float* __restrict__ outFused)
{
  __shared__ uint4 ldsq[576];
  unsigned int* ldsu = (unsigned int*)ldsq;
  const int l = threadIdx.x & 63, wid = threadIdx.x >> 6;
  const int p = l & 15, g = l >> 4;
  const int pt = blockIdx.x*64 + wid*16 + p;
  const f4v FZ = {0.f,0.f,0.f,0.f};

#define RELAYOUT(H, OB) { \
    _Pragma("unroll") \
    for (int m_=0;m_<4;m_++){ \
      unsigned int lo_ = (unsigned int)(unsigned short)f2bs(H[m_][0]) \
                       | ((unsigned int)(unsigned short)f2bs(H[m_][1])<<16); \
      unsigned int hi_ = (unsigned int)(unsigned short)f2bs(H[m_][2]) \
                       | ((unsigned int)(unsigned short)f2bs(H[m_][3])<<16); \
      int di_ = wid*576 + p*36 + m_*8 + g*2; \
      ldsu[di_] = lo_; ldsu[di_+1] = hi_; \
    } \
    OB[0] = __builtin_bit_cast(s8v, ldsq[wid*144 + p*9 + g]); \
    OB[1] = __builtin_bit_cast(s8v, ldsq[wid*144 + p*9 + 4 + g]); \
  }

  s8v fb[3][2];
  #pragma unroll
  for (int t=0;t<3;t++){
    const float* fp = feats + (size_t)(pt*3+t)*64;
    #pragma unroll
    for (int kc=0;kc<2;kc++){
      f4v a0 = *(const f4v*)(fp + kc*32 + g*8);
      f4v a1 = *(const f4v*)(fp + kc*32 + g*8 + 4);
      s8v tmp;
      #pragma unroll
      for (int e=0;e<4;e++){ tmp[e] = f2bs(a0[e]); tmp[e+4] = f2bs(a1[e]); }
      fb[t][kc] = tmp;
    }
  }

  float rd0 = raydir[(size_t)pt*3+0];
  float rd1 = raydir[(size_t)pt*3+1];
  float rd2 = raydir[(size_t)pt*3+2];
  s8v xb[2];
  #pragma unroll
  for (int kc=0;kc<2;kc++){
    s8v tmp;
    #pragma unroll
    for (int e=0;e<8;e++){
      int j = kc*32 + g*8 + e;
      float hv = fmaxf(rb1[j] + rw1[j*3]*rd0 + rw1[j*3+1]*rd1 + rw1[j*3+2]*rd2, 0.f);
      tmp[e] = f2bs(hv);
    }
    xb[kc] = tmp;
  }

  f4v acc[4];
  #pragma unroll
  for (int m=0;m<4;m++) acc[m] = FZ;
  #pragma unroll
  for (int kc=0;kc<2;kc++){
    #pragma unroll
    for (int m=0;m<4;m++)
      acc[m] = __builtin_amdgcn_mfma_f32_16x16x32_bf16(AFRG(rw2b), xb[kc], acc[m], 0,0,0);
  }
  float rf[4][4];
  #pragma unroll
  for (int m=0;m<4;m++){
    f4v bb = *(const f4v*)(rb2 + m*16 + g*4);
    #pragma unroll
    for (int r=0;r<4;r++) rf[m][r] = acc[m][r] + bb[r];
  }
  RELAYOUT(rf, xb);

  #pragma unroll
  for (int m=0;m<4;m++) acc[m] = FZ;
  #pragma unroll
  for (int kc=0;kc<2;kc++){
    #pragma unroll
    for (int m=0;m<4;m++)
      acc[m] = __builtin_amdgcn_mfma_f32_16x16x32_bf16(AFRG(wqb), xb[kc], acc[m], 0,0,0);
  }
  float qh[4][4];
  #pragma unroll
  for (int m=0;m<4;m++){
    f4v bb = *(const f4v*)(bq + m*16 + g*4);
    #pragma unroll
    for (int r=0;r<4;r++) qh[m][r] = acc[m][r] + bb[r];
  }

  s8v wkf[2][4];
  #pragma unroll
  for (int kc=0;kc<2;kc++)
    #pragma unroll
    for (int m=0;m<4;m++)
      wkf[kc][m] = AFRG(wkb);

  float sc[3][4];
  #pragma unroll
  for (int t=0;t<3;t++){
    f4v ka[4];
    #pragma unroll
    for (int m=0;m<4;m++) ka[m] = FZ;
    #pragma unroll
    for (int kc=0;kc<2;kc++){
      #pragma unroll
      for (int m=0;m<4;m++)
        ka[m] = __builtin_amdgcn_mfma_f32_16x16x32_bf16(wkf[kc][m], fb[t][kc], ka[m], 0,0,0);
    }
    #pragma unroll
    for (int m=0;m<4;m++){
      f4v bb = *(const f4v*)(bk + m*16 + g*4);
      float part = 0.f;
      #pragma unroll
      for (int r=0;r<4;r++) part += qh[m][r]*(ka[m][r] + bb[r]);
      part += __shfl_xor(part, 16, 64);
      part += __shfl_xor(part, 32, 64);
      sc[t][m] = part*0.25f;
    }
  }

  #pragma unroll
  for (int m=0;m<4;m++){
    float mx = fmaxf(fmaxf(sc[0][m], sc[1][m]), sc[2][m]);
    float e0 = __expf(sc[0][m]-mx);
    float e1 = __expf(sc[1][m]-mx);
    float e2 = __expf(sc[2][m]-mx);
    float inv = 1.f/(e0+e1+e2);
    sc[0][m] = e0*inv; sc[1][m] = e1*inv; sc[2][m] = e2*inv;
  }

  s8v wvf[2][4];
  #pragma unroll
  for (int kc=0;kc<2;kc++)
    #pragma unroll
    for (int m=0;m<4;m++)
      wvf[kc][m] = AFRG(wvb);

  float o[4][4];
  #pragma unroll
  for (int m=0;m<4;m++)
    #pragma unroll
    for (int r=0;r<4;r++) o[m][r] = 0.f;
  #pragma unroll
  for (int t=0;t<3;t++){
    f4v va[4];
    #pragma unroll
    for (int m=0;m<4;m++) va[m] = FZ;
    #pragma unroll
    for (int kc=0;kc<2;kc++){
      #pragma unroll
      for (int m=0;m<4;m++)
        va[m] = __builtin_amdgcn_mfma_f32_16x16x32_bf16(wvf[kc][m], fb[t][kc], va[m], 0,0,0);
    }
    #pragma unroll
    for (int m=0;m<4;m++)
      #pragma unroll
      for (int r=0;r<4;r++) o[m][r] += sc[t][m]*va[m][r];
  }
  #pragma unroll
  for (int m=0;m<4;m++){
    f4v bb = *(const f4v*)(bv + m*16 + g*4);
    #pragma unroll
    for (int r=0;r<4;r++) o[m][r] += bb[r];
  }
  RELAYOUT(o, xb);

  #pragma unroll
  for (int m=0;m<4;m++) acc[m] = FZ;
  #pragma unroll
  for (int kc=0;kc<2;kc++){
    #pragma unroll
    for (int m=0;m<4;m++)
      acc[m] = __builtin_amdgcn_mfma_f32_16x16x32_bf16(AFRG(wob), xb[kc], acc[m], 0,0,0);
  }
  #pragma unroll
  for (int m=0;m<4;m++){
    f4v bb = *(const f4v*)(bo + m*16 + g*4);
    f4v res;
    #pragma unroll
    for (int r=0;r<4;r++) res[r] = acc[m][r] + bb[r];
    *(f4v*)(outFused + (size_t)pt*64 + m*16 + g*4) = res;
  }
#undef RELAYOUT
}

extern "C" void kernel_launch(void* const* d_in, const int* in_sizes, int n_in,
                              void* d_out, int out_size, void* d_ws, size_t ws_size,
                              hipStream_t stream)
{
  const float* view_tex = (const float*)d_in[0];
  const float* uvi    = (const float*)d_in[1];
  const float* raydir = (const float*)d_in[2];
  const float* w1 = (const float*)d_in[3];
  const float* b1 = (const float*)d_in[4];
  const float* w2 = (const float*)d_in[5];
  const float* b2 = (const float*)d_in[6];
  const float* w3 = (const float*)d_in[7];
  const float* b3 = (const float*)d_in[8];
  const float* rw1 = (const float*)d_in[9];
  const float* rb1 = (const float*)d_in[10];
  const float* rw2 = (const float*)d_in[11];
  const float* rb2 = (const float*)d_in[12];
  const float* wq = (const float*)d_in[13];
  const float* bq = (const float*)d_in[14];
  const float* wk = (const float*)d_in[15];
  const float* bk = (const float*)d_in[16];
  const float* wv = (const float*)d_in[17];
  const float* bv = (const float*)d_in[18];
  const float* wo = (const float*)d_in[19];
  const float* bo = (const float*)d_in[20];
  float* out = (float*)d_out;

  const int V = in_sizes[0] / (3*512*512);     // 8
  const int B = in_sizes[1] / 9;               // 262144
  const size_t FEATS_OFF = (size_t)B*64;

  const size_t C2F  = (size_t)V*256*256*64*2;
  const size_t C2V  = (size_t)256*256*64*2;
  const size_t NTSB = (size_t)V*128*128*64*2;
  const size_t WREG = 262144;

  char* base = (char*)d_ws;
  bool full = (ws_size >= C2F + NTSB + WREG);

  char *c2, *ntsp, *wreg;
  if (full){
    c2 = base; ntsp = c2 + C2F; wreg = ntsp + NTSB;
  } else {
    c2 = base; ntsp = c2 + C2V; wreg = ntsp + NTSB;
  }
  short* w1b = (short*)(wreg);
  short* w2b = (short*)(wreg + 3456);
  short* w3b = (short*)(wreg + 40320);
  short* rw2b = (short*)(wreg + 114048);
  short* wqb  = (short*)(wreg + 122240);
  short* wkb  = (short*)(wreg + 130432);
  short* wvb  = (short*)(wreg + 138624);
  short* wob  = (short*)(wreg + 146816);

  k0_prep<<<dim3(300),256,0,stream>>>(w1,w2,w3,rw2,wq,wk,wv,wo,wreg);

  if (full){
    kc12<<<dim3(4,128,V),256,0,stream>>>(view_tex,(short*)c2,w1b,b1,w2b,b2,0);
    conv_mfma<64,2><<<dim3(1,128,V),256,0,stream>>>((const short*)c2,(short*)ntsp,w3b,b3,256,256,128,0);
  } else {
    for (int v=0; v<V; v++){
      kc12<<<dim3(4,128,1),256,0,stream>>>(view_tex,(short*)c2,w1b,b1,w2b,b2,v);
      conv_mfma<64,2><<<dim3(1,128,1),256,0,stream>>>((const short*)c2,(short*)ntsp,w3b,b3,256,256,128,v);
    }
  }

  k4_gather<<<dim3((B*3*8)/256),256,0,stream>>>((const short*)ntsp, uvi, out + FEATS_OFF);

  k5_attn<<<dim3(B/64),256,0,stream>>>(out + FEATS_OFF, raydir,
      rw1, rb1, rw2b, rb2, wqb, bq, wkb, bk, wvb, bv, wob, bo, out);
}

// Round 11
// 308.514 us; speedup vs baseline: 2.1214x; 1.1017x over previous
//
#include <hip/hip_runtime.h>

typedef short s8v __attribute__((ext_vector_type(8)));
typedef short s4v __attribute__((ext_vector_type(4)));
typedef float f4v __attribute__((ext_vector_type(4)));

#define DEV __device__ __forceinline__

DEV short f2bs(float f){
  unsigned int u = __float_as_uint(f);
  u += 0x7fffu + ((u >> 16) & 1u);
  return (short)(u >> 16);
}
DEV float b2f(short s){
  return __uint_as_float(((unsigned int)(unsigned short)s) << 16);
}
DEV float lrelu(float x){ return x >= 0.f ? x : 0.01f*x; }
DEV unsigned pk2(float a, float b){
  return (unsigned)(unsigned short)f2bs(a) | ((unsigned)(unsigned short)f2bs(b) << 16);
}

// ---------------- K0: weight prep ----------------
// wreg layout (bytes):
//   0      w1b  bf16 [m(2)][lane(64)][e(8)]  (2048 B; k=(lane>>4)*8+e, k>=27 -> 0)
//   3456   w2b  bf16 [tap][cout64][cin32]
//   40320  w3b  bf16 [tap][cout64][cin64]
//   114048 rw2b (unused) / 122240 wqrb (k0b) / 130432 wkb / 138624 wvb / 146816 wob
//   155008 bqr f32[64] (k0b)
__global__ __launch_bounds__(256) void k0_prep(
    const float* __restrict__ w1, const float* __restrict__ w2,
    const float* __restrict__ w3, const float* __restrict__ rw2,
    const float* __restrict__ wq, const float* __restrict__ wk,
    const float* __restrict__ wv, const float* __restrict__ wo,
    char* __restrict__ wreg)
{
  int idx = blockIdx.x*256 + threadIdx.x;
  short* w1b = (short*)(wreg);
  short* w2b = (short*)(wreg + 3456);
  short* w3b = (short*)(wreg + 40320);
  short* rw2b = (short*)(wreg + 114048);
  short* wkb  = (short*)(wreg + 130432);
  short* wvb  = (short*)(wreg + 138624);
  short* wob  = (short*)(wreg + 146816);
  if (idx < 1024){
    int e = idx & 7, l = (idx >> 3) & 63, m = idx >> 9;
    int k = (l >> 4)*8 + e;
    int cout = m*16 + (l & 15);
    w1b[idx] = (k < 27) ? f2bs(w1[cout*27 + k]) : (short)0;
  } else if (idx < 19456){
    int j = idx - 1024;
    int kk = j / 2048, c = (j >> 5) & 63, ci = j & 31;
    w2b[j] = f2bs(w2[c*288 + ci*9 + kk]);
  } else if (idx < 56320){
    int j = idx - 19456;
    int kk = j / 4096, c = (j >> 6) & 63, ci = j & 63;
    w3b[j] = f2bs(w3[c*576 + ci*9 + kk]);
  } else if (idx < 60416){
    int j = idx - 56320; rw2b[j] = f2bs(rw2[j]);
  } else if (idx < 64512){
    // skip (wqrb written by k0b)
  } else if (idx < 68608){
    int j = idx - 64512; wkb[j] = f2bs(wk[j]);
  } else if (idx < 72704){
    int j = idx - 68608; wvb[j] = f2bs(wv[j]);
  } else if (idx < 76800){
    int j = idx - 72704; wob[j] = f2bs(wo[j]);
  }
}

// ---------------- K0b: fold wq*rw2 -> wqrb (bf16), wq@rb2+bq -> bqr (f32) ----------------
__global__ __launch_bounds__(256) void k0b_fold(
    const float* __restrict__ wq, const float* __restrict__ rw2,
    const float* __restrict__ rb2, const float* __restrict__ bq,
    char* __restrict__ wreg)
{
  short* wqrb = (short*)(wreg + 122240);
  float* bqr  = (float*)(wreg + 155008);
  int tid = threadIdx.x;
  int i = tid >> 2, k0 = (tid & 3)*16;
  #pragma unroll
  for (int kk=0; kk<16; kk++){
    int k = k0 + kk;
    float s = 0.f;
    #pragma unroll
    for (int j=0; j<64; j++) s += wq[i*64+j]*rw2[j*64+k];
    wqrb[i*64+k] = f2bs(s);
  }
  if (tid < 64){
    float s = bq[tid];
    #pragma unroll
    for (int j=0; j<64; j++) s += wq[tid*64+j]*rb2[j];
    bqr[tid] = s;
  }
}

// ---------------- KC12: fused conv1+conv2 (unchanged from R10) ----------------
__global__ __launch_bounds__(256) void kc12(
    const float* __restrict__ vt, short* __restrict__ c2,
    const short* __restrict__ w1b, const float* __restrict__ b1,
    const short* __restrict__ w2b, const float* __restrict__ b2, int v0)
{
  __shared__ short srcT[3108];
  __shared__ short rb[4][2880];
  const int tid = threadIdx.x;
  const int l = tid & 63, wid = tid >> 6;
  const int p = l & 15, g = l >> 4;
  const int OXB = blockIdx.x*64, OYB = blockIdx.y*2;
  const float* src = vt + (size_t)(v0 + blockIdx.z)*3*512*512;

  #pragma unroll
  for (int it=0; it<13; it++){
    int idx = it*256 + tid;
    if (idx < 3108){
      int ci = idx/1036, rem = idx - ci*1036;
      int row = rem/148, col = rem - row*148;
      int gr = min(max(2*OYB - 2 + row, 0), 511);
      int gc = min(max(2*OXB - 2 + col, 0), 511);
      srcT[idx] = f2bs(src[((size_t)ci*512 + gr)*512 + gc]);
    }
  }

  int boffB[8];
  #pragma unroll
  for (int e=0;e<8;e++){
    int k = g*8 + e;
    int ci = (k*57) >> 9;
    int r9 = k - ci*9;
    int dy = (r9*11) >> 5;
    int dx = r9 - dy*3;
    boffB[e] = (k < 27) ? (ci*1036 + dy*148 + dx) : 0;
  }
  s8v af0 = *(const s8v*)(w1b + l*8);
  s8v af1 = *(const s8v*)(w1b + 512 + l*8);
  f4v cb0 = *(const f4v*)(b1 + g*4);
  f4v cb1 = *(const f4v*)(b1 + 16 + g*4);

  const int dlt = wid >> 1, h = wid & 1;
  const int oy = OYB + dlt;
  const int ox0 = OXB + h*32;
  const int Cw0 = 2*ox0 - 1;
  short* myrb = rb[wid];
  const f4v FZ = {0.f,0.f,0.f,0.f};
  f4v acc[2][4];
  #pragma unroll
  for (int s2=0;s2<2;s2++)
    #pragma unroll
    for (int m=0;m<4;m++) acc[s2][m] = FZ;

  __syncthreads();

  #pragma unroll
  for (int ky=0; ky<3; ky++){
    const int R = min(max(2*oy + ky - 1, 0), 511);
    const int trb = R - 2*OYB + 1;
    const int sbase = trb*148 + 64*h + p;

    #pragma unroll
    for (int s=0; s<5; s++){
      s8v bf;
      #pragma unroll
      for (int e=0;e<8;e++) bf[e] = srcT[boffB[e] + sbase + s*16];
      f4v d0 = __builtin_amdgcn_mfma_f32_16x16x32_bf16(af0, bf, FZ, 0,0,0);
      f4v d1 = __builtin_amdgcn_mfma_f32_16x16x32_bf16(af1, bf, FZ, 0,0,0);
      int wcol = s*16 + p;
      uint2 wa = { pk2(lrelu(d0[0]+cb0[0]), lrelu(d0[1]+cb0[1])),
                   pk2(lrelu(d0[2]+cb0[2]), lrelu(d0[3]+cb0[3])) };
      *(uint2*)(myrb + wcol*36 + g*4) = wa;
      uint2 wb2 = { pk2(lrelu(d1[0]+cb1[0]), lrelu(d1[1]+cb1[1])),
                    pk2(lrelu(d1[2]+cb1[2]), lrelu(d1[3]+cb1[3])) };
      *(uint2*)(myrb + wcol*36 + 16 + g*4) = wb2;
    }

    #pragma unroll
    for (int s2=0; s2<2; s2++){
      const int locox = s2*16 + p;
      #pragma unroll
      for (int kx=0; kx<3; kx++){
        int raw = Cw0 + 2*locox + kx;
        int ri = max(raw, 0) - Cw0;
        uint2 lo2 = *(const uint2*)(myrb + ri*36 + g*8);
        uint2 hi2 = *(const uint2*)(myrb + ri*36 + g*8 + 4);
        uint4 t4 = {lo2.x, lo2.y, hi2.x, hi2.y};
        s8v bf2 = __builtin_bit_cast(s8v, t4);
        #pragma unroll
        for (int m=0;m<4;m++){
          s8v afr = *(const s8v*)(w2b + ((ky*3+kx)*64 + m*16 + p)*32 + g*8);
          acc[s2][m] = __builtin_amdgcn_mfma_f32_16x16x32_bf16(afr, bf2, acc[s2][m], 0,0,0);
        }
      }
    }
  }

  #pragma unroll
  for (int s2=0; s2<2; s2++){
    short* o = c2 + (((size_t)blockIdx.z*256 + oy)*256 + ox0 + s2*16 + p)*64;
    #pragma unroll
    for (int m=0;m<4;m++){
      f4v bb = *(const f4v*)(b2 + m*16 + g*4);
      s4v pk;
      #pragma unroll
      for (int r=0;r<4;r++) pk[r] = f2bs(lrelu(acc[s2][m][r] + bb[r]));
      *(s4v*)(o + m*16 + g*4) = pk;
    }
  }
}

// ---------------- conv3: implicit-GEMM MFMA, stride 2 ----------------
template<int CIN, int TILES>
__global__ __launch_bounds__(256) void conv_mfma(
    const short* __restrict__ src0, short* __restrict__ dst,
    const short* __restrict__ wb, const float* __restrict__ bias,
    int IH, int IW, int OW, int dstV0)
{
  const int l = threadIdx.x & 63, w = threadIdx.x >> 6;
  const int p = l & 15, g = l >> 4;
  const int ox0 = blockIdx.x*(64*TILES) + w*(16*TILES) + p;
  const int oy = blockIdx.y;
  const short* src = src0 + (size_t)blockIdx.z*IH*IW*CIN;
  const f4v FZ = {0.f,0.f,0.f,0.f};
  f4v acc[TILES][4];
  #pragma unroll
  for (int tl=0;tl<TILES;tl++)
    #pragma unroll
    for (int m=0;m<4;m++) acc[tl][m] = FZ;
  #pragma unroll
  for (int ky=0;ky<3;ky++){
    int iy = min(max(2*oy+ky-1, 0), IH-1);
    #pragma unroll
    for (int kx=0;kx<3;kx++){
      #pragma unroll
      for (int ch=0; ch<CIN/32; ch++){
        s8v bfrag[TILES];
        #pragma unroll
        for (int tl=0;tl<TILES;tl++){
          int ix = min(max(2*(ox0 + 16*tl)+kx-1, 0), IW-1);
          bfrag[tl] = *(const s8v*)(src + ((size_t)iy*IW + ix)*CIN + ch*32 + g*8);
        }
        #pragma unroll
        for (int m=0;m<4;m++){
          s8v afrag = *(const s8v*)(wb + ((ky*3+kx)*64 + m*16 + p)*CIN + ch*32 + g*8);
          #pragma unroll
          for (int tl=0;tl<TILES;tl++)
            acc[tl][m] = __builtin_amdgcn_mfma_f32_16x16x32_bf16(afrag, bfrag[tl], acc[tl][m], 0,0,0);
        }
      }
    }
  }
  const int OH = gridDim.y;
  #pragma unroll
  for (int tl=0;tl<TILES;tl++){
    short* o = dst + (((size_t)(dstV0 + blockIdx.z)*OH + oy)*OW + ox0 + 16*tl)*64;
    #pragma unroll
    for (int m=0;m<4;m++){
      f4v bb = *(const f4v*)(bias + m*16 + g*4);
      s4v pk;
      #pragma unroll
      for (int r=0;r<4;r++) pk[r] = f2bs(lrelu(acc[tl][m][r] + bb[r]));
      *(s4v*)(o + m*16 + g*4) = pk;
    }
  }
}

// ---------------- K45: fused gather + rayMLP + MHA ----------------
// Block = 64 points. Phase 1: thread-parallel bilinear gather (thread = chunk
// ck = pt*24 + t*8 + c8), writes f32 feats (coalesced) + bf16 LDS [64][3][72].
// Phase 2: per-wave attention, fb B-frags read from LDS (2-way banks, free).
// Q path folded: qh = wqr@h + bqr (wqr = wq*rw2, from k0b).
#define AFRG(W) (*(const s8v*)((W) + (m*16 + p)*64 + kc*32 + g*8))

__global__ __launch_bounds__(256) void k45_fused(
    const short* __restrict__ nts, const float* __restrict__ uvi,
    const float* __restrict__ raydir,
    const float* __restrict__ rw1, const float* __restrict__ rb1,
    const short* __restrict__ wqrb, const float* __restrict__ bqr,
    const short* __restrict__ wkb, const float* __restrict__ bk,
    const short* __restrict__ wvb, const float* __restrict__ bv,
    const short* __restrict__ wob, const float* __restrict__ bo,
    float* __restrict__ outFused, float* __restrict__ outFeats)
{
  __shared__ short lds_fb[64*3*72];           // 27648 B
  const int tid = threadIdx.x;
  const int l = tid & 63, wid = tid >> 6;
  const int p = l & 15, g = l >> 4;
  const int pt0 = blockIdx.x*64;
  const f4v FZ = {0.f,0.f,0.f,0.f};

  // ---- phase 1: gather 64 pts x 3 tok x 64 ch ----
  #pragma unroll
  for (int i=0; i<6; i++){
    int ck = i*256 + tid;                     // [0,1536)
    int ptl = ck/24, rem = ck - ptl*24;
    int t = rem >> 3, c8 = rem & 7;
    int pt = pt0 + ptl;
    const float* up = uvi + (size_t)pt*9 + t*3;
    float u = up[0], v = up[1];
    int vid = (int)up[2];
    float xf = u*127.f, yf = v*127.f;
    int x0 = min(max((int)floorf(xf), 0), 126);
    int y0 = min(max((int)floorf(yf), 0), 126);
    float wx = xf - (float)x0, wy = yf - (float)y0;
    const short* cb = nts + ((size_t)((vid*128 + y0)*128 + x0))*64 + c8*8;
    s8v c00 = *(const s8v*)(cb);
    s8v c01 = *(const s8v*)(cb + 64);
    s8v c10 = *(const s8v*)(cb + 8192);
    s8v c11 = *(const s8v*)(cb + 8192 + 64);
    f4v o0, o1;
    s8v pk;
    #pragma unroll
    for (int e=0;e<8;e++){
      float a = b2f(c00[e]); a += wx*(b2f(c01[e]) - a);
      float b = b2f(c10[e]); b += wx*(b2f(c11[e]) - b);
      float val = a + wy*(b - a);
      if (e < 4) o0[e] = val; else o1[e-4] = val;
      pk[e] = f2bs(val);
    }
    float* op = outFeats + ((size_t)pt*3 + t)*64 + c8*8;
    *(f4v*)op = o0;
    *(f4v*)(op+4) = o1;
    *(s8v*)(&lds_fb[(ptl*3 + t)*72 + c8*8]) = pk;
  }

  __syncthreads();

  // ---- phase 2: attention. wave wid owns pts [wid*16, wid*16+16) ----
  const int ptl16 = wid*16 + p;
  const int pt = pt0 + ptl16;

  s8v fb[3][2];
  #pragma unroll
  for (int t=0;t<3;t++)
    #pragma unroll
    for (int kc=0;kc<2;kc++)
      fb[t][kc] = *(const s8v*)(&lds_fb[(ptl16*3 + t)*72 + kc*32 + g*8]);

  // ray MLP hidden in B-frag layout
  float rd0 = raydir[(size_t)pt*3+0];
  float rd1 = raydir[(size_t)pt*3+1];
  float rd2 = raydir[(size_t)pt*3+2];
  s8v xb[2];
  #pragma unroll
  for (int kc=0;kc<2;kc++){
    s8v tmp;
    #pragma unroll
    for (int e=0;e<8;e++){
      int j = kc*32 + g*8 + e;
      float hv = fmaxf(rb1[j] + rw1[j*3]*rd0 + rw1[j*3+1]*rd1 + rw1[j*3+2]*rd2, 0.f);
      tmp[e] = f2bs(hv);
    }
    xb[kc] = tmp;
  }

  // qh = wqr @ h + bqr   (D-frag)
  f4v acc[4];
  #pragma unroll
  for (int m=0;m<4;m++) acc[m] = FZ;
  #pragma unroll
  for (int kc=0;kc<2;kc++){
    #pragma unroll
    for (int m=0;m<4;m++)
      acc[m] = __builtin_amdgcn_mfma_f32_16x16x32_bf16(AFRG(wqrb), xb[kc], acc[m], 0,0,0);
  }
  float qh[4][4];
  #pragma unroll
  for (int m=0;m<4;m++){
    f4v bb = *(const f4v*)(bqr + m*16 + g*4);
    #pragma unroll
    for (int r=0;r<4;r++) qh[m][r] = acc[m][r] + bb[r];
  }

  // K projections + scores
  s8v wkf[2][4];
  #pragma unroll
  for (int kc=0;kc<2;kc++)
    #pragma unroll
    for (int m=0;m<4;m++)
      wkf[kc][m] = AFRG(wkb);

  float sc[3][4];
  #pragma unroll
  for (int t=0;t<3;t++){
    f4v ka[4];
    #pragma unroll
    for (int m=0;m<4;m++) ka[m] = FZ;
    #pragma unroll
    for (int kc=0;kc<2;kc++){
      #pragma unroll
      for (int m=0;m<4;m++)
        ka[m] = __builtin_amdgcn_mfma_f32_16x16x32_bf16(wkf[kc][m], fb[t][kc], ka[m], 0,0,0);
    }
    #pragma unroll
    for (int m=0;m<4;m++){
      f4v bb = *(const f4v*)(bk + m*16 + g*4);
      float part = 0.f;
      #pragma unroll
      for (int r=0;r<4;r++) part += qh[m][r]*(ka[m][r] + bb[r]);
      part += __shfl_xor(part, 16, 64);
      part += __shfl_xor(part, 32, 64);
      sc[t][m] = part*0.25f;
    }
  }

  // softmax over 3 tokens
  #pragma unroll
  for (int m=0;m<4;m++){
    float mx = fmaxf(fmaxf(sc[0][m], sc[1][m]), sc[2][m]);
    float e0 = __expf(sc[0][m]-mx);
    float e1 = __expf(sc[1][m]-mx);
    float e2 = __expf(sc[2][m]-mx);
    float inv = 1.f/(e0+e1+e2);
    sc[0][m] = e0*inv; sc[1][m] = e1*inv; sc[2][m] = e2*inv;
  }

  // V projections, scaled accumulation (bv added once; sum(e)=1)
  s8v wvf[2][4];
  #pragma unroll
  for (int kc=0;kc<2;kc++)
    #pragma unroll
    for (int m=0;m<4;m++)
      wvf[kc][m] = AFRG(wvb);

  float o[4][4];
  #pragma unroll
  for (int m=0;m<4;m++)
    #pragma unroll
    for (int r=0;r<4;r++) o[m][r] = 0.f;
  #pragma unroll
  for (int t=0;t<3;t++){
    f4v va[4];
    #pragma unroll
    for (int m=0;m<4;m++) va[m] = FZ;
    #pragma unroll
    for (int kc=0;kc<2;kc++){
      #pragma unroll
      for (int m=0;m<4;m++)
        va[m] = __builtin_amdgcn_mfma_f32_16x16x32_bf16(wvf[kc][m], fb[t][kc], va[m], 0,0,0);
    }
    #pragma unroll
    for (int m=0;m<4;m++)
      #pragma unroll
      for (int r=0;r<4;r++) o[m][r] += sc[t][m]*va[m][r];
  }
  #pragma unroll
  for (int m=0;m<4;m++){
    f4v bb = *(const f4v*)(bv + m*16 + g*4);
    #pragma unroll
    for (int r=0;r<4;r++) o[m][r] += bb[r];
  }

  // relayout o (D-frag) -> B-frag, reusing this wave's dead lds_fb region
  {
    unsigned* rl = (unsigned*)lds_fb + wid*1728;
    #pragma unroll
    for (int m=0;m<4;m++){
      unsigned lo = pk2(o[m][0], o[m][1]);
      unsigned hi = pk2(o[m][2], o[m][3]);
      rl[p*36 + m*8 + g*2] = lo;
      rl[p*36 + m*8 + g*2 + 1] = hi;
    }
    xb[0] = __builtin_bit_cast(s8v, *(uint4*)(rl + p*36 + g*4));
    xb[1] = __builtin_bit_cast(s8v, *(uint4*)(rl + p*36 + 16 + g*4));
  }

  // out = wo @ o + bo
  #pragma unroll
  for (int m=0;m<4;m++) acc[m] = FZ;
  #pragma unroll
  for (int kc=0;kc<2;kc++){
    #pragma unroll
    for (int m=0;m<4;m++)
      acc[m] = __builtin_amdgcn_mfma_f32_16x16x32_bf16(AFRG(wob), xb[kc], acc[m], 0,0,0);
  }
  #pragma unroll
  for (int m=0;m<4;m++){
    f4v bb = *(const f4v*)(bo + m*16 + g*4);
    f4v res;
    #pragma unroll
    for (int r=0;r<4;r++) res[r] = acc[m][r] + bb[r];
    *(f4v*)(outFused + (size_t)pt*64 + m*16 + g*4) = res;
  }
}

extern "C" void kernel_launch(void* const* d_in, const int* in_sizes, int n_in,
                              void* d_out, int out_size, void* d_ws, size_t ws_size,
                              hipStream_t stream)
{
  const float* view_tex = (const float*)d_in[0];
  const float* uvi    = (const float*)d_in[1];
  const float* raydir = (const float*)d_in[2];
  const float* w1 = (const float*)d_in[3];
  const float* b1 = (const float*)d_in[4];
  const float* w2 = (const float*)d_in[5];
  const float* b2 = (const float*)d_in[6];
  const float* w3 = (const float*)d_in[7];
  const float* b3 = (const float*)d_in[8];
  const float* rw1 = (const float*)d_in[9];
  const float* rb1 = (const float*)d_in[10];
  const float* rw2 = (const float*)d_in[11];
  const float* rb2 = (const float*)d_in[12];
  const float* wq = (const float*)d_in[13];
  const float* bq = (const float*)d_in[14];
  const float* wk = (const float*)d_in[15];
  const float* bk = (const float*)d_in[16];
  const float* wv = (const float*)d_in[17];
  const float* bv = (const float*)d_in[18];
  const float* wo = (const float*)d_in[19];
  const float* bo = (const float*)d_in[20];
  float* out = (float*)d_out;

  const int V = in_sizes[0] / (3*512*512);     // 8
  const int B = in_sizes[1] / 9;               // 262144
  const size_t FEATS_OFF = (size_t)B*64;

  const size_t C2F  = (size_t)V*256*256*64*2;
  const size_t C2V  = (size_t)256*256*64*2;
  const size_t NTSB = (size_t)V*128*128*64*2;
  const size_t WREG = 262144;

  char* base = (char*)d_ws;
  bool full = (ws_size >= C2F + NTSB + WREG);

  char *c2, *ntsp, *wreg;
  if (full){
    c2 = base; ntsp = c2 + C2F; wreg = ntsp + NTSB;
  } else {
    c2 = base; ntsp = c2 + C2V; wreg = ntsp + NTSB;
  }
  short* w1b = (short*)(wreg);
  short* w2b = (short*)(wreg + 3456);
  short* w3b = (short*)(wreg + 40320);
  short* wqrb = (short*)(wreg + 122240);
  short* wkb  = (short*)(wreg + 130432);
  short* wvb  = (short*)(wreg + 138624);
  short* wob  = (short*)(wreg + 146816);
  float* bqr  = (float*)(wreg + 155008);

  k0_prep<<<dim3(300),256,0,stream>>>(w1,w2,w3,rw2,wq,wk,wv,wo,wreg);
  k0b_fold<<<dim3(1),256,0,stream>>>(wq, rw2, rb2, bq, wreg);

  if (full){
    kc12<<<dim3(4,128,V),256,0,stream>>>(view_tex,(short*)c2,w1b,b1,w2b,b2,0);
    conv_mfma<64,2><<<dim3(1,128,V),256,0,stream>>>((const short*)c2,(short*)ntsp,w3b,b3,256,256,128,0);
  } else {
    for (int v=0; v<V; v++){
      kc12<<<dim3(4,128,1),256,0,stream>>>(view_tex,(short*)c2,w1b,b1,w2b,b2,v);
      conv_mfma<64,2><<<dim3(1,128,1),256,0,stream>>>((const short*)c2,(short*)ntsp,w3b,b3,256,256,128,v);
    }
  }

  k45_fused<<<dim3(B/64),256,0,stream>>>((const short*)ntsp, uvi, raydir,
      rw1, rb1, wqrb, bqr, wkb, bk, wvb, bv, wob, bo,
      out, out + FEATS_OFF);
}